// Round 6
// baseline (629.962 us; speedup 1.0000x reference)
//
#include <hip/hip_runtime.h>

#define BN_EPS 1e-5f

typedef _Float16 f16;
typedef _Float16 f16x8 __attribute__((ext_vector_type(8)));
typedef _Float16 f16x4 __attribute__((ext_vector_type(4)));
typedef float f32x4 __attribute__((ext_vector_type(4)));
typedef int i32x4 __attribute__((ext_vector_type(4)));   // clang vec for nt builtins

#define NBLK 512      // chunks in bucket count/scatter passes
#define BSHIFT 8      // bucket = dst >> 8  (256 nodes/bucket)
#define BMASK 255

// ======= wfrag mapping: W [FIN,FOUT] f32 -> MFMA-frag-ordered f16 =============
// stats may be NC strided copies (stride 2*FIN): sum then BN-scale.
__device__ __forceinline__ void wfrag_one(const float* __restrict__ W, f16* __restrict__ out,
        int FIN, int FOUT, int f,
        const float* __restrict__ stats, int NC, const float* __restrict__ g, float invN) {
    int j = f & 7;
    int lane = (f >> 3) & 63;
    int tile = f >> 9;
    int NT = FOUT >> 4;
    int t = tile % NT, s = tile / NT;
    int k = s * 32 + (lane >> 4) * 8 + j;
    int n = t * 16 + (lane & 15);
    float w = W[(size_t)k * FOUT + n];
    if (stats) {
        float s1 = 0.0f, s2 = 0.0f;
        for (int c = 0; c < NC; c++) {
            s1 += stats[c * 2 * FIN + k];
            s2 += stats[c * 2 * FIN + FIN + k];
        }
        float mu = s1 * invN;
        float var = fmaxf(s2 * invN - mu * mu, 0.0f);
        w *= rsqrtf(var + BN_EPS) * g[k];
    }
    out[f] = (f16)w;
}

// ========== fused setup: x->f16 conv + static W frags + bucket count ==========
__global__ __launch_bounds__(256) void setup_count(const float4* __restrict__ x,
        f16x4* __restrict__ xh, int n4,
        const float* __restrict__ W1a, f16* __restrict__ Wh1a,
        const float* __restrict__ W1b, f16* __restrict__ Wh1b,
        const float* __restrict__ W2b, f16* __restrict__ Wh2b,
        const float* __restrict__ W3b, f16* __restrict__ Wh3b,
        const int* __restrict__ dst, int* __restrict__ hist,
        int NBK, int CHUNK, int E) {
    __shared__ int lh[512];
    const int BC = (n4 + 255) / 256;
    int bid = blockIdx.x;
    const int t = threadIdx.x;
    if (bid < BC) {
        int i = bid * 256 + t;
        if (i < n4) {
            const float* xp = (const float*)&x[i];
            float v0 = __builtin_nontemporal_load(xp + 0);   // read-once stream
            float v1 = __builtin_nontemporal_load(xp + 1);
            float v2 = __builtin_nontemporal_load(xp + 2);
            float v3 = __builtin_nontemporal_load(xp + 3);
            f16x4 o;
            o.x = (f16)v0; o.y = (f16)v1; o.z = (f16)v2; o.w = (f16)v3;
            xh[i] = o;   // normal store: xh is the layer-1 gather table
        }
        return;
    }
    bid -= BC;
    if (bid < 116) {
        if (bid < 32)       wfrag_one(W1a, Wh1a, 64, 128, bid * 256 + t, nullptr, 1, nullptr, 0.f);
        else if (bid < 96)  wfrag_one(W1b, Wh1b, 128, 128, (bid - 32) * 256 + t, nullptr, 1, nullptr, 0.f);
        else if (bid < 112) wfrag_one(W2b, Wh2b, 64, 64, (bid - 96) * 256 + t, nullptr, 1, nullptr, 0.f);
        else                wfrag_one(W3b, Wh3b, 32, 32, (bid - 112) * 256 + t, nullptr, 1, nullptr, 0.f);
        return;
    }
    const int blk = bid - 116;   // chunk id, one per block
    for (int r = t; r < 512; r += 256) lh[r] = 0;
    __syncthreads();
    const int e0 = blk * CHUNK, e1 = min(E, e0 + CHUNK);
    const int nq = (e1 - e0) >> 2;
    const i32x4* d4 = (const i32x4*)(dst + e0);
    for (int q = t; q < nq; q += 256) {
        i32x4 v = __builtin_nontemporal_load(&d4[q]);        // read-once stream
        atomicAdd(&lh[v.x >> BSHIFT], 1);
        atomicAdd(&lh[v.y >> BSHIFT], 1);
        atomicAdd(&lh[v.z >> BSHIFT], 1);
        atomicAdd(&lh[v.w >> BSHIFT], 1);
    }
    for (int e = e0 + (nq << 2) + t; e < e1; e += 256) atomicAdd(&lh[dst[e] >> BSHIFT], 1);
    __syncthreads();
    for (int r = t; r < NBK; r += 256) hist[r * NBLK + blk] = lh[r];
}

// per-bucket exclusive scan over chunk counts; emit bucket totals
__global__ __launch_bounds__(512) void bkt_bscan(int* __restrict__ hist,
        int* __restrict__ btot) {
    __shared__ int sh[512];
    const int b = blockIdx.x, t = threadIdx.x;
    int v = hist[b * NBLK + t];
    sh[t] = v;
    __syncthreads();
    for (int d = 1; d < 512; d <<= 1) {
        int u = (t >= d) ? sh[t - d] : 0;
        __syncthreads();
        sh[t] += u;
        __syncthreads();
    }
    hist[b * NBLK + t] = sh[t] - v;        // exclusive
    if (t == 511) btot[b] = sh[511];
}

// scatter packed (local_dst<<18 | src); computes bucket bases from btot in LDS
__global__ __launch_bounds__(512) void bkt_scatter(const int* __restrict__ src,
        const int* __restrict__ dst, const int* __restrict__ hist,
        const int* __restrict__ btot, int* __restrict__ bucketed,
        int NBK, int CHUNK, int E) {
    __shared__ int sc[512];
    __shared__ int lc[512];
    const int blk = blockIdx.x, t = threadIdx.x;
    int v = (t < NBK) ? btot[t] : 0;
    sc[t] = v;
    __syncthreads();
    for (int d = 1; d < 512; d <<= 1) {
        int u = (t >= d) ? sc[t - d] : 0;
        __syncthreads();
        sc[t] += u;
        __syncthreads();
    }
    if (t < NBK) lc[t] = (sc[t] - v) + hist[t * NBLK + blk];
    __syncthreads();
    const int e0 = blk * CHUNK, e1 = min(E, e0 + CHUNK);
    const int nq = (e1 - e0) >> 2;
    const i32x4* d4 = (const i32x4*)(dst + e0);
    const i32x4* s4 = (const i32x4*)(src + e0);
    for (int q = t; q < nq; q += 512) {
        i32x4 d = __builtin_nontemporal_load(&d4[q]);        // read-once streams
        i32x4 s = __builtin_nontemporal_load(&s4[q]);
        int sl;
        sl = atomicAdd(&lc[d.x >> BSHIFT], 1); __builtin_nontemporal_store(((d.x & BMASK) << 18) | s.x, &bucketed[sl]);
        sl = atomicAdd(&lc[d.y >> BSHIFT], 1); __builtin_nontemporal_store(((d.y & BMASK) << 18) | s.y, &bucketed[sl]);
        sl = atomicAdd(&lc[d.z >> BSHIFT], 1); __builtin_nontemporal_store(((d.z & BMASK) << 18) | s.z, &bucketed[sl]);
        sl = atomicAdd(&lc[d.w >> BSHIFT], 1); __builtin_nontemporal_store(((d.w & BMASK) << 18) | s.w, &bucketed[sl]);
    }
    for (int e = e0 + (nq << 2) + t; e < e1; e += 512) {
        int d = dst[e];
        int slot = atomicAdd(&lc[d >> BSHIFT], 1);
        __builtin_nontemporal_store(((d & BMASK) << 18) | src[e], &bucketed[slot]);
    }
}

// per-bucket CSR finalize; computes own boff from btot in LDS
// (bucketed is read TWICE per block within a short window -> keep normal loads)
__global__ __launch_bounds__(512) void bkt_csr(const int* __restrict__ bucketed,
        const int* __restrict__ btot, int* __restrict__ off,
        int* __restrict__ elist, int NBK, int N, int E) {
    __shared__ int sc[512];
    __shared__ int lh[256];
    __shared__ int lc[256];
    __shared__ int sh[256];
    const int b = blockIdx.x, t = threadIdx.x;
    int v = (t < NBK) ? btot[t] : 0;
    sc[t] = v;
    __syncthreads();
    for (int d = 1; d < 512; d <<= 1) {
        int u = (t >= d) ? sc[t - d] : 0;
        __syncthreads();
        sc[t] += u;
        __syncthreads();
    }
    const int cnt  = btot[b];
    const int base = sc[b] - cnt;        // exclusive boff[b]
    if (b == 0 && t == 0) off[N] = E;
    const int b0 = b << BSHIFT;
    const int R = min(N - b0, 256);
    if (t < 256) lh[t] = 0;
    __syncthreads();
    for (int i = t; i < cnt; i += 512) atomicAdd(&lh[bucketed[base + i] >> 18], 1);
    __syncthreads();
    int v0 = 0;
    if (t < 256) { v0 = lh[t]; sh[t] = v0; }
    __syncthreads();
    for (int d = 1; d < 256; d <<= 1) {
        int u = 0;
        if (t < 256 && t >= d) u = sh[t - d];
        __syncthreads();
        if (t < 256) sh[t] += u;
        __syncthreads();
    }
    if (t < 256) { int ex = sh[t] - v0; lh[t] = ex; lc[t] = ex; }
    __syncthreads();
    if (t < R) off[b0 + t] = base + lh[t];
    for (int i = t; i < cnt; i += 512) {
        int p = bucketed[base + i];
        int rk = atomicAdd(&lc[p >> 18], 1);
        __builtin_nontemporal_store(p & 0x3FFFF, &elist[base + rk]);
    }
}

// ============ fused gather (+affine) -> LDS -> MFMA GEMM (+relu,+stats) =======
// A block gathers NPB consecutive node rows into LDS, then its 4 waves run the
// following F->FOUT GEMM on those SPB row-stripes. Stats go to 8 strided copies.
// Row-major gather: TPN lanes share one 128B row -> 8 cache lines/wave (good).
// 4-deep pipeline is the measured optimum. nt hints keep the random-read table
// resident in L2: elist (read-once) and Out (write-once) bypass allocation.
template<int F, int FOUT, bool STATS, bool AFFINE, typename OutT>
__global__ __launch_bounds__(256) void gather_gemm(const int* __restrict__ off,
        const int* __restrict__ elist, const f16* __restrict__ in,
        const f16* __restrict__ Wf, const float* __restrict__ bias,
        const float* __restrict__ av, const float* __restrict__ ab,
        OutT* __restrict__ Out, float* __restrict__ stats, int N) {
    constexpr int TPN = F / 8;         // lanes per node in gather
    constexpr int NPB = 256 / TPN;     // nodes per block
    constexpr int SPB = NPB / 16;      // 16-row stripes per block
    constexpr int WPS = 4 / SPB;       // waves per stripe
    constexpr int NTF = FOUT / 16;     // total n-tiles
    constexpr int NTW = NTF / WPS;     // n-tiles per wave
    constexpr int NS = F / 32;         // k-steps
    constexpr int LDW = F + 8;         // LDS row stride (f16), +16B pad
    __shared__ f16 Hl[NPB * LDW];
    __shared__ float Ss[STATS ? 2 * FOUT : 1];
    if (STATS) for (int z = threadIdx.x; z < 2 * FOUT; z += 256) Ss[z] = 0.0f;

    const int base = blockIdx.x * NPB;
    const int rl = threadIdx.x / TPN;
    const int i = base + rl;
    const int l = threadIdx.x & (TPN - 1);
    if (i < N) {
        const int j0 = l * 8;
        const f16x8* __restrict__ inv = (const f16x8*)in;
        f16x8 s = inv[(size_t)i * TPN + l];
        float a[8];
#pragma unroll
        for (int u = 0; u < 8; u++) a[u] = (float)s[u];
        int k = off[i], e = off[i + 1];
        const float cnt = (float)(e - k + 1);
        f16x8 c0, c1, c2, c3;
        if (k + 4 <= e) {
            int i0 = __builtin_nontemporal_load(&elist[k + 0]);
            int i1 = __builtin_nontemporal_load(&elist[k + 1]);
            int i2 = __builtin_nontemporal_load(&elist[k + 2]);
            int i3 = __builtin_nontemporal_load(&elist[k + 3]);
            c0 = inv[(size_t)i0 * TPN + l];
            c1 = inv[(size_t)i1 * TPN + l];
            c2 = inv[(size_t)i2 * TPN + l];
            c3 = inv[(size_t)i3 * TPN + l];
            k += 4;
            for (; k + 4 <= e; k += 4) {
                int j0i = __builtin_nontemporal_load(&elist[k + 0]);
                int j1i = __builtin_nontemporal_load(&elist[k + 1]);
                int j2i = __builtin_nontemporal_load(&elist[k + 2]);
                int j3i = __builtin_nontemporal_load(&elist[k + 3]);
                f16x8 d0 = inv[(size_t)j0i * TPN + l];
                f16x8 d1 = inv[(size_t)j1i * TPN + l];
                f16x8 d2 = inv[(size_t)j2i * TPN + l];
                f16x8 d3 = inv[(size_t)j3i * TPN + l];
#pragma unroll
                for (int u = 0; u < 8; u++)
                    a[u] += ((float)c0[u] + (float)c1[u]) + ((float)c2[u] + (float)c3[u]);
                c0 = d0; c1 = d1; c2 = d2; c3 = d3;
            }
#pragma unroll
            for (int u = 0; u < 8; u++)
                a[u] += ((float)c0[u] + (float)c1[u]) + ((float)c2[u] + (float)c3[u]);
        }
        for (; k < e; k++) {
            int ji = __builtin_nontemporal_load(&elist[k]);
            f16x8 p = inv[(size_t)ji * TPN + l];
#pragma unroll
            for (int u = 0; u < 8; u++) a[u] += (float)p[u];
        }
        if (AFFINE) {
            float4 vv0 = *(const float4*)(av + j0);
            float4 vv1 = *(const float4*)(av + j0 + 4);
            float4 bb0 = *(const float4*)(ab + j0);
            float4 bb1 = *(const float4*)(ab + j0 + 4);
            a[0] = fmaxf(fmaf(cnt, vv0.x, a[0] + bb0.x), 0.0f);
            a[1] = fmaxf(fmaf(cnt, vv0.y, a[1] + bb0.y), 0.0f);
            a[2] = fmaxf(fmaf(cnt, vv0.z, a[2] + bb0.z), 0.0f);
            a[3] = fmaxf(fmaf(cnt, vv0.w, a[3] + bb0.w), 0.0f);
            a[4] = fmaxf(fmaf(cnt, vv1.x, a[4] + bb1.x), 0.0f);
            a[5] = fmaxf(fmaf(cnt, vv1.y, a[5] + bb1.y), 0.0f);
            a[6] = fmaxf(fmaf(cnt, vv1.z, a[6] + bb1.z), 0.0f);
            a[7] = fmaxf(fmaf(cnt, vv1.w, a[7] + bb1.w), 0.0f);
        }
        f16x8 o;
#pragma unroll
        for (int u = 0; u < 8; u++) o[u] = (f16)a[u];
        *(f16x8*)&Hl[rl * LDW + j0] = o;
    }
    __syncthreads();

    const int wid = threadIdx.x >> 6;
    const int lane = threadIdx.x & 63;
    const int col = lane & 15;
    const int quad = lane >> 4;
    const int sid = wid / WPS;
    const int cg = wid % WPS;
    const int m0 = base + sid * 16;
    if (m0 < N) {
        f16x8 Bf[NS][NTW];
#pragma unroll
        for (int s = 0; s < NS; s++)
#pragma unroll
            for (int t = 0; t < NTW; t++)
                Bf[s][t] = *(const f16x8*)&Wf[((s * NTF + cg * NTW + t) << 9) + (lane << 3)];
        f32x4 acc[NTW];
#pragma unroll
        for (int t = 0; t < NTW; t++) {
            float b = bias[(cg * NTW + t) * 16 + col];
            acc[t] = (f32x4){b, b, b, b};
        }
        f16x8 Af[NS];
        const int rbase = (sid * 16 + col) * LDW + quad * 8;
#pragma unroll
        for (int s = 0; s < NS; s++) Af[s] = *(const f16x8*)&Hl[rbase + s * 32];
#pragma unroll
        for (int t = 0; t < NTW; t++)
#pragma unroll
            for (int s = 0; s < NS; s++)
                acc[t] = __builtin_amdgcn_mfma_f32_16x16x32_f16(Af[s], Bf[s][t], acc[t], 0, 0, 0);
#pragma unroll
        for (int t = 0; t < NTW; t++) {
            float v0 = fmaxf(acc[t][0], 0.0f);
            float v1 = fmaxf(acc[t][1], 0.0f);
            float v2 = fmaxf(acc[t][2], 0.0f);
            float v3 = fmaxf(acc[t][3], 0.0f);
            OutT* o = Out + (size_t)(m0 + quad * 4) * FOUT + (cg * NTW + t) * 16 + col;
            __builtin_nontemporal_store((OutT)v0, &o[0]);
            __builtin_nontemporal_store((OutT)v1, &o[FOUT]);
            __builtin_nontemporal_store((OutT)v2, &o[2 * FOUT]);
            __builtin_nontemporal_store((OutT)v3, &o[3 * FOUT]);
            if (STATS) {
                float s1 = (v0 + v1) + (v2 + v3);
                float s2 = (v0 * v0 + v1 * v1) + (v2 * v2 + v3 * v3);
                s1 += __shfl_xor(s1, 16); s1 += __shfl_xor(s1, 32);
                s2 += __shfl_xor(s2, 16); s2 += __shfl_xor(s2, 32);
                if (quad == 0) {
                    atomicAdd(&Ss[(cg * NTW + t) * 16 + col], s1);
                    atomicAdd(&Ss[FOUT + (cg * NTW + t) * 16 + col], s2);
                }
            }
        }
    }
    if (STATS) {
        __syncthreads();
        float* stc = stats + (blockIdx.x & 7) * 2 * FOUT;
        for (int z = threadIdx.x; z < 2 * FOUT; z += 256) atomicAdd(&stc[z], Ss[z]);
    }
}

// ===== fused layer prep: block 0 computes v[]; blocks 1.. do scaled wfrag =====
// Block 0 parallelizes the stats reduction across k (one thread per k-channel,
// sc/sh stashed in LDS): the serial FIN x NC form was a 76us straggler.
__global__ __launch_bounds__(256) void layerprep_kernel(const float* __restrict__ W,
        f16* __restrict__ Wh, int FIN, int FOUT,
        const float* __restrict__ stats, int NC, const float* __restrict__ g,
        const float* __restrict__ be, float* __restrict__ v, float invN) {
    if (blockIdx.x == 0) {
        __shared__ float sh_s[128];
        const int t = threadIdx.x;
        if (t < FIN) {
            float s1 = 0.0f, s2 = 0.0f;
            for (int c = 0; c < NC; c++) {
                s1 += stats[c * 2 * FIN + t];
                s2 += stats[c * 2 * FIN + FIN + t];
            }
            float mu = s1 * invN;
            float var = fmaxf(s2 * invN - mu * mu, 0.0f);
            float sc = rsqrtf(var + BN_EPS) * g[t];
            sh_s[t] = be[t] - mu * sc;
        }
        __syncthreads();
        for (int j = t; j < FOUT; j += 256) {
            float acc = 0.0f;
            for (int k = 0; k < FIN; k++)
                acc = fmaf(sh_s[k], W[(size_t)k * FOUT + j], acc);
            v[j] = acc;
        }
        return;
    }
    int f = (blockIdx.x - 1) * 256 + threadIdx.x;
    if (f < FIN * FOUT) wfrag_one(W, Wh, FIN, FOUT, f, stats, NC, g, invN);
}

// ======= standalone MFMA GEMM (pre-fragged W, column-block loop INSIDE) =======
// Column blocks iterate inside the stripe loop so A streams exactly once from
// HBM; Bf reloads per cb come from the L2-hot 32KB weight array. Stats go to
// 8 strided copies. A loads / Out stores are nt (read-once / write-once).
template<int FIN, int FOUT, int CT, bool STATS, bool RELU, bool BIAS, typename OutT>
__global__ __launch_bounds__(256) void gemm_mfma(const f16* __restrict__ A,
        const f16* __restrict__ Wf, const float* __restrict__ bias,
        OutT* __restrict__ Out, float* __restrict__ stats, int N) {
    constexpr int NS = FIN / 32;
    constexpr int NTF = FOUT / 16;
    constexpr int NT = CT / 16;
    constexpr int NCB = FOUT / CT;
    __shared__ float Ss[STATS ? 2 * FOUT : 1];
    if (STATS) {
        for (int i = threadIdx.x; i < 2 * FOUT; i += 256) Ss[i] = 0.0f;
        __syncthreads();
    }
    const int rb = blockIdx.x;
    const int RB = gridDim.x;
    const int wid = threadIdx.x >> 6;
    const int lane = threadIdx.x & 63;
    const int col = lane & 15;
    const int quad = lane >> 4;

    float bj[NCB][NT];
#pragma unroll
    for (int cb = 0; cb < NCB; cb++)
#pragma unroll
        for (int t = 0; t < NT; t++)
            bj[cb][t] = BIAS ? bias[(cb * NT + t) * 16 + col] : 0.0f;

    float ls[NCB][NT], ls2[NCB][NT];
#pragma unroll
    for (int cb = 0; cb < NCB; cb++)
#pragma unroll
        for (int t = 0; t < NT; t++) { ls[cb][t] = 0.0f; ls2[cb][t] = 0.0f; }

    const int S = N >> 4;
    for (int sidx = rb * 4 + wid; sidx < S; sidx += RB * 4) {
        const int m0 = sidx << 4;
        const f16* a0 = A + (size_t)(m0 + col) * FIN + (quad << 3);
        f16x8 Af[NS];
#pragma unroll
        for (int s = 0; s < NS; s++) Af[s] = __builtin_nontemporal_load((const f16x8*)(a0 + s * 32));
#pragma unroll
        for (int cb = 0; cb < NCB; cb++) {
            const int t0 = cb * NT;
            f16x8 Bf[NS][NT];
#pragma unroll
            for (int s = 0; s < NS; s++)
#pragma unroll
                for (int t = 0; t < NT; t++)
                    Bf[s][t] = *(const f16x8*)&Wf[((s * NTF + t0 + t) << 9) + (lane << 3)];
            f32x4 acc[NT];
#pragma unroll
            for (int t = 0; t < NT; t++) acc[t] = (f32x4){bj[cb][t], bj[cb][t], bj[cb][t], bj[cb][t]};
#pragma unroll
            for (int t = 0; t < NT; t++)
#pragma unroll
                for (int s = 0; s < NS; s++)
                    acc[t] = __builtin_amdgcn_mfma_f32_16x16x32_f16(Af[s], Bf[s][t], acc[t], 0, 0, 0);
#pragma unroll
            for (int t = 0; t < NT; t++) {
                float v0 = acc[t][0], v1 = acc[t][1], v2 = acc[t][2], v3 = acc[t][3];
                if (RELU) {
                    v0 = fmaxf(v0, 0.0f); v1 = fmaxf(v1, 0.0f);
                    v2 = fmaxf(v2, 0.0f); v3 = fmaxf(v3, 0.0f);
                }
                if (STATS) {
                    ls[cb][t]  += (v0 + v1) + (v2 + v3);
                    ls2[cb][t] += (v0 * v0 + v1 * v1) + (v2 * v2 + v3 * v3);
                }
                OutT* o = Out + (size_t)(m0 + quad * 4) * FOUT + (t0 + t) * 16 + col;
                __builtin_nontemporal_store((OutT)v0, &o[0]);
                __builtin_nontemporal_store((OutT)v1, &o[FOUT]);
                __builtin_nontemporal_store((OutT)v2, &o[2 * FOUT]);
                __builtin_nontemporal_store((OutT)v3, &o[3 * FOUT]);
            }
        }
    }

    if (STATS) {
#pragma unroll
        for (int cb = 0; cb < NCB; cb++)
#pragma unroll
            for (int t = 0; t < NT; t++) {
                float s1 = ls[cb][t], s2 = ls2[cb][t];
                s1 += __shfl_xor(s1, 16); s1 += __shfl_xor(s1, 32);
                s2 += __shfl_xor(s2, 16); s2 += __shfl_xor(s2, 32);
                if (quad == 0) {
                    atomicAdd(&Ss[(cb * NT + t) * 16 + col], s1);
                    atomicAdd(&Ss[FOUT + (cb * NT + t) * 16 + col], s2);
                }
            }
        __syncthreads();
        float* stc = stats + (blockIdx.x & 7) * 2 * FOUT;
        for (int i = threadIdx.x; i < 2 * FOUT; i += 256) atomicAdd(&stc[i], Ss[i]);
    }
}

// ========= layer-3 BN + segmented pool (batch sorted; stats = NC copies) ======
__global__ __launch_bounds__(256) void bn_pool_kernel(const float* __restrict__ y,
        const float* __restrict__ stats, int NC, const float* __restrict__ gw,
        const float* __restrict__ bw, const int* __restrict__ batch,
        float* __restrict__ pool, int N, float invN) {
    constexpr int F = 32, CH = 64;
    int q = threadIdx.x >> 5;
    int j = threadIdx.x & 31;
    int r0 = (blockIdx.x * 8 + q) * CH;
    if (r0 >= N) return;
    int r1 = min(r0 + CH, N);
    float s1 = 0.0f, s2 = 0.0f;
    for (int c = 0; c < NC; c++) {
        s1 += stats[c * 2 * F + j];
        s2 += stats[c * 2 * F + F + j];
    }
    float mu = s1 * invN;
    float var = fmaxf(s2 * invN - mu * mu, 0.0f);
    float sc = rsqrtf(var + BN_EPS) * gw[j];
    float sh = bw[j] - mu * sc;
    int curg = batch[r0];
    float acc = 0.0f;
    for (int r = r0; r < r1; r++) {
        int g = batch[r];
        if (g != curg) {
            atomicAdd(pool + (size_t)curg * 32 + j, acc);
            acc = 0.0f;
            curg = g;
        }
        acc = fmaf(__builtin_nontemporal_load(&y[(size_t)r * 32 + j]), sc, sh + acc);
    }
    atomicAdd(pool + (size_t)curg * 32 + j, acc);
}

// ================= FC head =================
__global__ __launch_bounds__(128) void fc_kernel(const float* __restrict__ pool,
        const float* __restrict__ Wf1, const float* __restrict__ bf1,
        const float* __restrict__ Wf2, const float* __restrict__ bf2,
        const float* __restrict__ Wf3, const float* __restrict__ bf3,
        float* __restrict__ out) {
    __shared__ float zin[32];
    __shared__ float h1[128];
    __shared__ float h2[64];
    const int gidx = blockIdx.x;
    const int t = threadIdx.x;
    if (t < 32) zin[t] = pool[(size_t)gidx * 32 + t];
    __syncthreads();
    {
        float a = bf1[t];
        for (int k = 0; k < 32; k++) a = fmaf(zin[k], Wf1[k * 128 + t], a);
        h1[t] = fmaxf(a, 0.0f);
    }
    __syncthreads();
    if (t < 64) {
        float a = bf2[t];
        for (int k = 0; k < 128; k++) a = fmaf(h1[k], Wf2[k * 64 + t], a);
        h2[t] = fmaxf(a, 0.0f);
    }
    __syncthreads();
    if (t < 10) {
        float a = bf3[t];
        for (int k = 0; k < 64; k++) a = fmaf(h2[k], Wf3[k * 10 + t], a);
        out[(size_t)gidx * 10 + t] = a;
    }
}

extern "C" void kernel_launch(void* const* d_in, const int* in_sizes, int n_in,
                              void* d_out, int out_size, void* d_ws, size_t ws_size,
                              hipStream_t stream) {
    const float* x   = (const float*)d_in[0];
    const int*  ei   = (const int*)d_in[1];
    const int*  batch= (const int*)d_in[2];
    const float* W1a = (const float*)d_in[3];  const float* b1a = (const float*)d_in[4];
    const float* W1b = (const float*)d_in[5];  const float* b1b = (const float*)d_in[6];
    const float* g1  = (const float*)d_in[7];  const float* be1 = (const float*)d_in[8];
    const float* W2a = (const float*)d_in[9];  const float* b2a = (const float*)d_in[10];
    const float* W2b = (const float*)d_in[11]; const float* b2b = (const float*)d_in[12];
    const float* g2  = (const float*)d_in[13]; const float* be2 = (const float*)d_in[14];
    const float* W3a = (const float*)d_in[15]; const float* b3a = (const float*)d_in[16];
    const float* W3b = (const float*)d_in[17]; const float* b3b = (const float*)d_in[18];
    const float* g3  = (const float*)d_in[19]; const float* be3 = (const float*)d_in[20];
    const float* Wf1 = (const float*)d_in[21]; const float* bf1 = (const float*)d_in[22];
    const float* Wf2 = (const float*)d_in[23]; const float* bf2 = (const float*)d_in[24];
    const float* Wf3 = (const float*)d_in[25]; const float* bf3 = (const float*)d_in[26];

    const int N = in_sizes[2];
    const int E = in_sizes[1] / 2;
    const int G = out_size / 10;
    const int* src = ei;
    const int* dst = ei + E;

    const int NBK = (N + BMASK) >> BSHIFT;           // 391 for N=100K
    const int CHUNK = (((E + NBLK - 1) / NBLK) + 3) & ~3;  // 4-aligned

    // ---- ws layout ----
    float* B0   = (float*)d_ws;              // N*128 f32 worth (= N*256 f16)
    float* B1   = B0 + (size_t)N * 128;
    float* pool = B1 + (size_t)N * 128;      // G*32
    float* st1  = pool + (size_t)G * 32;     // 8 * 256 (8 strided copies)
    float* st2c = st1 + 2048;                // 8 * 128
    float* st3c = st2c + 1024;               // 8 * 64
    int* off    = (int*)(st3c + 512);        // N+1
    int* elist  = off + (N + 1);             // E
    float* v2   = (float*)(elist + E);       // 64
    float* v3   = v2 + 64;                   // 32
    int* btot   = (int*)(v3 + 32);           // NBK
    f16* Wh1a   = (f16*)(btot + NBK);        // 8K
    f16* Wh1b   = Wh1a + 64 * 128;           // 16K
    f16* Wh2a   = Wh1b + 128 * 128;          // 8K
    f16* Wh2b   = Wh2a + 128 * 64;           // 4K
    f16* Wh3a   = Wh2b + 64 * 64;            // 2K
    f16* Wh3b   = Wh3a + 64 * 32;            // 1K

    // ---- CSR-phase aliases in B1 (dead before B1's activation use) ----
    int* bucketed = (int*)B1;                // E ints (12.8 MB)
    int* hist     = bucketed + E;            // NBK*NBLK ints (800 KB)

    // ---- activation aliases (stream-order safe) ----
    f16* xh    = (f16*)B0;                    // N*64  [B0 slot A]
    f16* H1    = (f16*)B0 + (size_t)N * 64;   // N*128 [B0 slot B]
    f16* Y1    = (f16*)B1 + (size_t)N * 64;   // N*128 [B1 slot B] (hist dead)
    f16* Z1    = (f16*)B0;                    // N*64  [B0 slot A] (xh dead)
    f16* Y2    = (f16*)B0 + (size_t)N * 64;   // N*64  [B0 slot B] (H1 dead)
    f16* Z2    = (f16*)B0;                    // N*32  [B0 slot A] (Z1 dead)
    float* Y3  = B1 + (size_t)N * 64;         // N*32 f32 [B1 slot B] (Y1 dead)

    hipMemsetAsync(pool, 0, ((size_t)G * 32 + 2048 + 1024 + 512) * sizeof(float), stream);

    const float invN = 1.0f / (float)N;
    const int GG = 640;

    // ---- fused setup: conv + static W frags + bucket count ----
    {
        int BC = (N * 16 + 255) / 256;
        setup_count<<<BC + 116 + NBLK, 256, 0, stream>>>(
            (const float4*)x, (f16x4*)xh, N * 16,
            W1a, Wh1a, W1b, Wh1b, W2b, Wh2b, W3b, Wh3b,
            dst, hist, NBK, CHUNK, E);
    }

    // ---- CSR build ----
    bkt_bscan  <<<NBK, 512, 0, stream>>>(hist, btot);
    bkt_scatter<<<NBLK, 512, 0, stream>>>(src, dst, hist, btot, bucketed, NBK, CHUNK, E);
    bkt_csr    <<<NBK, 512, 0, stream>>>(bucketed, btot, off, elist, NBK, N, E);

    // ---- Layer 1: [gather1 + gemm1a] fused -> gemm1b(stats st1, 8 copies) ----
    gather_gemm<64, 128, false, false, f16><<<(N + 31) / 32, 256, 0, stream>>>(
        off, elist, xh, Wh1a, b1a, nullptr, nullptr, H1, nullptr, N);
    gemm_mfma<128, 128, 64, true, true, true, f16><<<GG, 256, 0, stream>>>(H1, Wh1b, b1b, Y1, st1, N);

    // ---- Layer 2 (commuted): prep -> gemm2a -> [gather2 + gemm2b(stats st2c)] ----
    layerprep_kernel<<<33, 256, 0, stream>>>(W2a, Wh2a, 128, 64, st1, 8, g1, be1, v2, invN);
    gemm_mfma<128, 64, 64, false, false, false, f16><<<GG, 256, 0, stream>>>(Y1, Wh2a, nullptr, Z1, nullptr, N);
    gather_gemm<64, 64, true, true, f16><<<(N + 31) / 32, 256, 0, stream>>>(
        off, elist, Z1, Wh2b, b2b, v2, b2a, Y2, st2c, N);

    // ---- Layer 3 (commuted): prep -> gemm3a -> [gather3 + gemm3b(stats st3c)] ----
    layerprep_kernel<<<9, 256, 0, stream>>>(W3a, Wh3a, 64, 32, st2c, 8, g2, be2, v3, invN);
    gemm_mfma<64, 32, 32, false, false, false, f16><<<GG, 256, 0, stream>>>(Y2, Wh3a, nullptr, Z2, nullptr, N);
    gather_gemm<32, 32, true, true, float><<<(N + 63) / 64, 256, 0, stream>>>(
        off, elist, Z2, Wh3b, b3b, v3, b3a, Y3, st3c, N);

    // ---- BN3 + segmented pool ----
    bn_pool_kernel<<<(N + 511) / 512, 256, 0, stream>>>(Y3, st3c, 8, g3, be3, batch, pool, N, invN);

    // ---- pooled MLP head ----
    fc_kernel<<<G, 128, 0, stream>>>(pool, Wf1, bf1, Wf2, bf2, Wf3, bf3, (float*)d_out);
}

// Round 9
// 475.418 us; speedup vs baseline: 1.3251x; 1.3251x over previous
//
#include <hip/hip_runtime.h>

#define BN_EPS 1e-5f

typedef _Float16 f16;
typedef _Float16 f16x8 __attribute__((ext_vector_type(8)));
typedef _Float16 f16x4 __attribute__((ext_vector_type(4)));
typedef float f32x4 __attribute__((ext_vector_type(4)));
typedef int i32x4 __attribute__((ext_vector_type(4)));   // clang vec for nt builtins

#define NBLK 512      // chunks in bucket count/scatter passes
#define BSHIFT 8      // bucket = dst >> 8  (256 nodes/bucket)
#define BMASK 255

// ======= wfrag mapping: W [FIN,FOUT] f32 -> MFMA-frag-ordered f16 =============
// stats may be NC strided copies (stride 2*FIN): sum then BN-scale.
__device__ __forceinline__ void wfrag_one(const float* __restrict__ W, f16* __restrict__ out,
        int FIN, int FOUT, int f,
        const float* __restrict__ stats, int NC, const float* __restrict__ g, float invN) {
    int j = f & 7;
    int lane = (f >> 3) & 63;
    int tile = f >> 9;
    int NT = FOUT >> 4;
    int t = tile % NT, s = tile / NT;
    int k = s * 32 + (lane >> 4) * 8 + j;
    int n = t * 16 + (lane & 15);
    float w = W[(size_t)k * FOUT + n];
    if (stats) {
        float s1 = 0.0f, s2 = 0.0f;
        for (int c = 0; c < NC; c++) {
            s1 += stats[c * 2 * FIN + k];
            s2 += stats[c * 2 * FIN + FIN + k];
        }
        float mu = s1 * invN;
        float var = fmaxf(s2 * invN - mu * mu, 0.0f);
        w *= rsqrtf(var + BN_EPS) * g[k];
    }
    out[f] = (f16)w;
}

// ========== fused setup: x->f16 conv + static W frags + bucket count ==========
__global__ __launch_bounds__(256) void setup_count(const float4* __restrict__ x,
        f16x4* __restrict__ xh, int n4,
        const float* __restrict__ W1a, f16* __restrict__ Wh1a,
        const float* __restrict__ W1b, f16* __restrict__ Wh1b,
        const float* __restrict__ W2b, f16* __restrict__ Wh2b,
        const float* __restrict__ W3b, f16* __restrict__ Wh3b,
        const int* __restrict__ dst, int* __restrict__ hist,
        int NBK, int CHUNK, int E) {
    __shared__ int lh[512];
    const int BC = (n4 + 255) / 256;
    int bid = blockIdx.x;
    const int t = threadIdx.x;
    if (bid < BC) {
        int i = bid * 256 + t;
        if (i < n4) {
            f32x4 v = __builtin_nontemporal_load((const f32x4*)&x[i]);  // read-once
            f16x4 o;
            o.x = (f16)v.x; o.y = (f16)v.y; o.z = (f16)v.z; o.w = (f16)v.w;
            xh[i] = o;   // normal store: xh is the layer-1 gather table
        }
        return;
    }
    bid -= BC;
    if (bid < 116) {
        if (bid < 32)       wfrag_one(W1a, Wh1a, 64, 128, bid * 256 + t, nullptr, 1, nullptr, 0.f);
        else if (bid < 96)  wfrag_one(W1b, Wh1b, 128, 128, (bid - 32) * 256 + t, nullptr, 1, nullptr, 0.f);
        else if (bid < 112) wfrag_one(W2b, Wh2b, 64, 64, (bid - 96) * 256 + t, nullptr, 1, nullptr, 0.f);
        else                wfrag_one(W3b, Wh3b, 32, 32, (bid - 112) * 256 + t, nullptr, 1, nullptr, 0.f);
        return;
    }
    const int blk = bid - 116;   // chunk id, one per block
    for (int r = t; r < 512; r += 256) lh[r] = 0;
    __syncthreads();
    const int e0 = blk * CHUNK, e1 = min(E, e0 + CHUNK);
    const int nq = (e1 - e0) >> 2;
    const i32x4* d4 = (const i32x4*)(dst + e0);
    for (int q = t; q < nq; q += 256) {
        i32x4 v = __builtin_nontemporal_load(&d4[q]);        // read-once stream
        atomicAdd(&lh[v.x >> BSHIFT], 1);
        atomicAdd(&lh[v.y >> BSHIFT], 1);
        atomicAdd(&lh[v.z >> BSHIFT], 1);
        atomicAdd(&lh[v.w >> BSHIFT], 1);
    }
    for (int e = e0 + (nq << 2) + t; e < e1; e += 256) atomicAdd(&lh[dst[e] >> BSHIFT], 1);
    __syncthreads();
    for (int r = t; r < NBK; r += 256) hist[r * NBLK + blk] = lh[r];
}

// per-bucket exclusive scan over chunk counts; emit bucket totals
__global__ __launch_bounds__(512) void bkt_bscan(int* __restrict__ hist,
        int* __restrict__ btot) {
    __shared__ int sh[512];
    const int b = blockIdx.x, t = threadIdx.x;
    int v = hist[b * NBLK + t];
    sh[t] = v;
    __syncthreads();
    for (int d = 1; d < 512; d <<= 1) {
        int u = (t >= d) ? sh[t - d] : 0;
        __syncthreads();
        sh[t] += u;
        __syncthreads();
    }
    hist[b * NBLK + t] = sh[t] - v;        // exclusive
    if (t == 511) btot[b] = sh[511];
}

// scatter packed (local_dst<<18 | src); computes bucket bases from btot in LDS
// NOTE: scattered stores MUST be normal stores — nt-stores on scattered 4B
// writes bypass L2 write-combining and amplify HBM writes ~16x (measured r6).
__global__ __launch_bounds__(512) void bkt_scatter(const int* __restrict__ src,
        const int* __restrict__ dst, const int* __restrict__ hist,
        const int* __restrict__ btot, int* __restrict__ bucketed,
        int NBK, int CHUNK, int E) {
    __shared__ int sc[512];
    __shared__ int lc[512];
    const int blk = blockIdx.x, t = threadIdx.x;
    int v = (t < NBK) ? btot[t] : 0;
    sc[t] = v;
    __syncthreads();
    for (int d = 1; d < 512; d <<= 1) {
        int u = (t >= d) ? sc[t - d] : 0;
        __syncthreads();
        sc[t] += u;
        __syncthreads();
    }
    if (t < NBK) lc[t] = (sc[t] - v) + hist[t * NBLK + blk];
    __syncthreads();
    const int e0 = blk * CHUNK, e1 = min(E, e0 + CHUNK);
    const int nq = (e1 - e0) >> 2;
    const i32x4* d4 = (const i32x4*)(dst + e0);
    const i32x4* s4 = (const i32x4*)(src + e0);
    for (int q = t; q < nq; q += 512) {
        i32x4 d = __builtin_nontemporal_load(&d4[q]);        // read-once streams
        i32x4 s = __builtin_nontemporal_load(&s4[q]);
        int sl;
        sl = atomicAdd(&lc[d.x >> BSHIFT], 1); bucketed[sl] = ((d.x & BMASK) << 18) | s.x;
        sl = atomicAdd(&lc[d.y >> BSHIFT], 1); bucketed[sl] = ((d.y & BMASK) << 18) | s.y;
        sl = atomicAdd(&lc[d.z >> BSHIFT], 1); bucketed[sl] = ((d.z & BMASK) << 18) | s.z;
        sl = atomicAdd(&lc[d.w >> BSHIFT], 1); bucketed[sl] = ((d.w & BMASK) << 18) | s.w;
    }
    for (int e = e0 + (nq << 2) + t; e < e1; e += 512) {
        int d = dst[e];
        int slot = atomicAdd(&lc[d >> BSHIFT], 1);
        bucketed[slot] = ((d & BMASK) << 18) | src[e];
    }
}

// per-bucket CSR finalize; computes own boff from btot in LDS
// (scattered elist writes: normal stores — see r6 nt-store write-amplification)
__global__ __launch_bounds__(512) void bkt_csr(const int* __restrict__ bucketed,
        const int* __restrict__ btot, int* __restrict__ off,
        int* __restrict__ elist, int NBK, int N, int E) {
    __shared__ int sc[512];
    __shared__ int lh[256];
    __shared__ int lc[256];
    __shared__ int sh[256];
    const int b = blockIdx.x, t = threadIdx.x;
    int v = (t < NBK) ? btot[t] : 0;
    sc[t] = v;
    __syncthreads();
    for (int d = 1; d < 512; d <<= 1) {
        int u = (t >= d) ? sc[t - d] : 0;
        __syncthreads();
        sc[t] += u;
        __syncthreads();
    }
    const int cnt  = btot[b];
    const int base = sc[b] - cnt;        // exclusive boff[b]
    if (b == 0 && t == 0) off[N] = E;
    const int b0 = b << BSHIFT;
    const int R = min(N - b0, 256);
    if (t < 256) lh[t] = 0;
    __syncthreads();
    for (int i = t; i < cnt; i += 512) atomicAdd(&lh[bucketed[base + i] >> 18], 1);
    __syncthreads();
    int v0 = 0;
    if (t < 256) { v0 = lh[t]; sh[t] = v0; }
    __syncthreads();
    for (int d = 1; d < 256; d <<= 1) {
        int u = 0;
        if (t < 256 && t >= d) u = sh[t - d];
        __syncthreads();
        if (t < 256) sh[t] += u;
        __syncthreads();
    }
    if (t < 256) { int ex = sh[t] - v0; lh[t] = ex; lc[t] = ex; }
    __syncthreads();
    if (t < R) off[b0 + t] = base + lh[t];
    for (int i = t; i < cnt; i += 512) {
        int p = bucketed[base + i];
        int rk = atomicAdd(&lc[p >> 18], 1);
        elist[base + rk] = p & 0x3FFFF;
    }
}

// ============ fused gather (+affine) -> LDS -> MFMA GEMM (+relu,+stats) =======
// A block gathers NPB consecutive node rows into LDS, then its 4 waves run the
// following F->FOUT GEMM on those SPB row-stripes. Stats go to 8 strided copies.
// Row-major gather: TPN lanes share one 128B row -> 8 cache lines/wave (good).
// 4-deep pipeline is the measured optimum. elist reads are nt (read-once) so
// they don't evict the hot random-read table from L2. All stores normal.
template<int F, int FOUT, bool STATS, bool AFFINE, typename OutT>
__global__ __launch_bounds__(256) void gather_gemm(const int* __restrict__ off,
        const int* __restrict__ elist, const f16* __restrict__ in,
        const f16* __restrict__ Wf, const float* __restrict__ bias,
        const float* __restrict__ av, const float* __restrict__ ab,
        OutT* __restrict__ Out, float* __restrict__ stats, int N) {
    constexpr int TPN = F / 8;         // lanes per node in gather
    constexpr int NPB = 256 / TPN;     // nodes per block
    constexpr int SPB = NPB / 16;      // 16-row stripes per block
    constexpr int WPS = 4 / SPB;       // waves per stripe
    constexpr int NTF = FOUT / 16;     // total n-tiles
    constexpr int NTW = NTF / WPS;     // n-tiles per wave
    constexpr int NS = F / 32;         // k-steps
    constexpr int LDW = F + 8;         // LDS row stride (f16), +16B pad
    __shared__ f16 Hl[NPB * LDW];
    __shared__ float Ss[STATS ? 2 * FOUT : 1];
    if (STATS) for (int z = threadIdx.x; z < 2 * FOUT; z += 256) Ss[z] = 0.0f;

    const int base = blockIdx.x * NPB;
    const int rl = threadIdx.x / TPN;
    const int i = base + rl;
    const int l = threadIdx.x & (TPN - 1);
    if (i < N) {
        const int j0 = l * 8;
        const f16x8* __restrict__ inv = (const f16x8*)in;
        f16x8 s = inv[(size_t)i * TPN + l];
        float a[8];
#pragma unroll
        for (int u = 0; u < 8; u++) a[u] = (float)s[u];
        int k = off[i], e = off[i + 1];
        const float cnt = (float)(e - k + 1);
        f16x8 c0, c1, c2, c3;
        if (k + 4 <= e) {
            int i0 = __builtin_nontemporal_load(&elist[k + 0]);
            int i1 = __builtin_nontemporal_load(&elist[k + 1]);
            int i2 = __builtin_nontemporal_load(&elist[k + 2]);
            int i3 = __builtin_nontemporal_load(&elist[k + 3]);
            c0 = inv[(size_t)i0 * TPN + l];
            c1 = inv[(size_t)i1 * TPN + l];
            c2 = inv[(size_t)i2 * TPN + l];
            c3 = inv[(size_t)i3 * TPN + l];
            k += 4;
            for (; k + 4 <= e; k += 4) {
                int j0i = __builtin_nontemporal_load(&elist[k + 0]);
                int j1i = __builtin_nontemporal_load(&elist[k + 1]);
                int j2i = __builtin_nontemporal_load(&elist[k + 2]);
                int j3i = __builtin_nontemporal_load(&elist[k + 3]);
                f16x8 d0 = inv[(size_t)j0i * TPN + l];
                f16x8 d1 = inv[(size_t)j1i * TPN + l];
                f16x8 d2 = inv[(size_t)j2i * TPN + l];
                f16x8 d3 = inv[(size_t)j3i * TPN + l];
#pragma unroll
                for (int u = 0; u < 8; u++)
                    a[u] += ((float)c0[u] + (float)c1[u]) + ((float)c2[u] + (float)c3[u]);
                c0 = d0; c1 = d1; c2 = d2; c3 = d3;
            }
#pragma unroll
            for (int u = 0; u < 8; u++)
                a[u] += ((float)c0[u] + (float)c1[u]) + ((float)c2[u] + (float)c3[u]);
        }
        for (; k < e; k++) {
            int ji = __builtin_nontemporal_load(&elist[k]);
            f16x8 p = inv[(size_t)ji * TPN + l];
#pragma unroll
            for (int u = 0; u < 8; u++) a[u] += (float)p[u];
        }
        if (AFFINE) {
            float4 vv0 = *(const float4*)(av + j0);
            float4 vv1 = *(const float4*)(av + j0 + 4);
            float4 bb0 = *(const float4*)(ab + j0);
            float4 bb1 = *(const float4*)(ab + j0 + 4);
            a[0] = fmaxf(fmaf(cnt, vv0.x, a[0] + bb0.x), 0.0f);
            a[1] = fmaxf(fmaf(cnt, vv0.y, a[1] + bb0.y), 0.0f);
            a[2] = fmaxf(fmaf(cnt, vv0.z, a[2] + bb0.z), 0.0f);
            a[3] = fmaxf(fmaf(cnt, vv0.w, a[3] + bb0.w), 0.0f);
            a[4] = fmaxf(fmaf(cnt, vv1.x, a[4] + bb1.x), 0.0f);
            a[5] = fmaxf(fmaf(cnt, vv1.y, a[5] + bb1.y), 0.0f);
            a[6] = fmaxf(fmaf(cnt, vv1.z, a[6] + bb1.z), 0.0f);
            a[7] = fmaxf(fmaf(cnt, vv1.w, a[7] + bb1.w), 0.0f);
        }
        f16x8 o;
#pragma unroll
        for (int u = 0; u < 8; u++) o[u] = (f16)a[u];
        *(f16x8*)&Hl[rl * LDW + j0] = o;
    }
    __syncthreads();

    const int wid = threadIdx.x >> 6;
    const int lane = threadIdx.x & 63;
    const int col = lane & 15;
    const int quad = lane >> 4;
    const int sid = wid / WPS;
    const int cg = wid % WPS;
    const int m0 = base + sid * 16;
    if (m0 < N) {
        f16x8 Bf[NS][NTW];
#pragma unroll
        for (int s = 0; s < NS; s++)
#pragma unroll
            for (int t = 0; t < NTW; t++)
                Bf[s][t] = *(const f16x8*)&Wf[((s * NTF + cg * NTW + t) << 9) + (lane << 3)];
        f32x4 acc[NTW];
#pragma unroll
        for (int t = 0; t < NTW; t++) {
            float b = bias[(cg * NTW + t) * 16 + col];
            acc[t] = (f32x4){b, b, b, b};
        }
        f16x8 Af[NS];
        const int rbase = (sid * 16 + col) * LDW + quad * 8;
#pragma unroll
        for (int s = 0; s < NS; s++) Af[s] = *(const f16x8*)&Hl[rbase + s * 32];
#pragma unroll
        for (int t = 0; t < NTW; t++)
#pragma unroll
            for (int s = 0; s < NS; s++)
                acc[t] = __builtin_amdgcn_mfma_f32_16x16x32_f16(Af[s], Bf[s][t], acc[t], 0, 0, 0);
#pragma unroll
        for (int t = 0; t < NTW; t++) {
            float v0 = fmaxf(acc[t][0], 0.0f);
            float v1 = fmaxf(acc[t][1], 0.0f);
            float v2 = fmaxf(acc[t][2], 0.0f);
            float v3 = fmaxf(acc[t][3], 0.0f);
            OutT* o = Out + (size_t)(m0 + quad * 4) * FOUT + (cg * NTW + t) * 16 + col;
            o[0]        = (OutT)v0;
            o[FOUT]     = (OutT)v1;
            o[2 * FOUT] = (OutT)v2;
            o[3 * FOUT] = (OutT)v3;
            if (STATS) {
                float s1 = (v0 + v1) + (v2 + v3);
                float s2 = (v0 * v0 + v1 * v1) + (v2 * v2 + v3 * v3);
                s1 += __shfl_xor(s1, 16); s1 += __shfl_xor(s1, 32);
                s2 += __shfl_xor(s2, 16); s2 += __shfl_xor(s2, 32);
                if (quad == 0) {
                    atomicAdd(&Ss[(cg * NTW + t) * 16 + col], s1);
                    atomicAdd(&Ss[FOUT + (cg * NTW + t) * 16 + col], s2);
                }
            }
        }
    }
    if (STATS) {
        __syncthreads();
        float* stc = stats + (blockIdx.x & 7) * 2 * FOUT;
        for (int z = threadIdx.x; z < 2 * FOUT; z += 256) atomicAdd(&stc[z], Ss[z]);
    }
}

// ===== fused layer prep: block 0 computes v[]; blocks 1.. do scaled wfrag =====
// Block 0 parallelizes the stats reduction across k (one thread per k-channel,
// sc/sh stashed in LDS): the serial FIN x NC form was a 76us straggler.
__global__ __launch_bounds__(256) void layerprep_kernel(const float* __restrict__ W,
        f16* __restrict__ Wh, int FIN, int FOUT,
        const float* __restrict__ stats, int NC, const float* __restrict__ g,
        const float* __restrict__ be, float* __restrict__ v, float invN) {
    if (blockIdx.x == 0) {
        __shared__ float sh_s[128];
        const int t = threadIdx.x;
        if (t < FIN) {
            float s1 = 0.0f, s2 = 0.0f;
            for (int c = 0; c < NC; c++) {
                s1 += stats[c * 2 * FIN + t];
                s2 += stats[c * 2 * FIN + FIN + t];
            }
            float mu = s1 * invN;
            float var = fmaxf(s2 * invN - mu * mu, 0.0f);
            float sc = rsqrtf(var + BN_EPS) * g[t];
            sh_s[t] = be[t] - mu * sc;
        }
        __syncthreads();
        for (int j = t; j < FOUT; j += 256) {
            float acc = 0.0f;
            for (int k = 0; k < FIN; k++)
                acc = fmaf(sh_s[k], W[(size_t)k * FOUT + j], acc);
            v[j] = acc;
        }
        return;
    }
    int f = (blockIdx.x - 1) * 256 + threadIdx.x;
    if (f < FIN * FOUT) wfrag_one(W, Wh, FIN, FOUT, f, stats, NC, g, invN);
}

// ======= standalone MFMA GEMM (pre-fragged W, column-block loop INSIDE) =======
// Column blocks iterate inside the stripe loop so A streams exactly once from
// HBM; Bf reloads per cb come from the L2-hot 32KB weight array. Stats go to
// 8 strided copies. A loads are nt (read-once); all stores normal.
template<int FIN, int FOUT, int CT, bool STATS, bool RELU, bool BIAS, typename OutT>
__global__ __launch_bounds__(256) void gemm_mfma(const f16* __restrict__ A,
        const f16* __restrict__ Wf, const float* __restrict__ bias,
        OutT* __restrict__ Out, float* __restrict__ stats, int N) {
    constexpr int NS = FIN / 32;
    constexpr int NTF = FOUT / 16;
    constexpr int NT = CT / 16;
    constexpr int NCB = FOUT / CT;
    __shared__ float Ss[STATS ? 2 * FOUT : 1];
    if (STATS) {
        for (int i = threadIdx.x; i < 2 * FOUT; i += 256) Ss[i] = 0.0f;
        __syncthreads();
    }
    const int rb = blockIdx.x;
    const int RB = gridDim.x;
    const int wid = threadIdx.x >> 6;
    const int lane = threadIdx.x & 63;
    const int col = lane & 15;
    const int quad = lane >> 4;

    float bj[NCB][NT];
#pragma unroll
    for (int cb = 0; cb < NCB; cb++)
#pragma unroll
        for (int t = 0; t < NT; t++)
            bj[cb][t] = BIAS ? bias[(cb * NT + t) * 16 + col] : 0.0f;

    float ls[NCB][NT], ls2[NCB][NT];
#pragma unroll
    for (int cb = 0; cb < NCB; cb++)
#pragma unroll
        for (int t = 0; t < NT; t++) { ls[cb][t] = 0.0f; ls2[cb][t] = 0.0f; }

    const int S = N >> 4;
    for (int sidx = rb * 4 + wid; sidx < S; sidx += RB * 4) {
        const int m0 = sidx << 4;
        const f16* a0 = A + (size_t)(m0 + col) * FIN + (quad << 3);
        f16x8 Af[NS];
#pragma unroll
        for (int s = 0; s < NS; s++) Af[s] = __builtin_nontemporal_load((const f16x8*)(a0 + s * 32));
#pragma unroll
        for (int cb = 0; cb < NCB; cb++) {
            const int t0 = cb * NT;
            f16x8 Bf[NS][NT];
#pragma unroll
            for (int s = 0; s < NS; s++)
#pragma unroll
                for (int t = 0; t < NT; t++)
                    Bf[s][t] = *(const f16x8*)&Wf[((s * NTF + t0 + t) << 9) + (lane << 3)];
            f32x4 acc[NT];
#pragma unroll
            for (int t = 0; t < NT; t++) acc[t] = (f32x4){bj[cb][t], bj[cb][t], bj[cb][t], bj[cb][t]};
#pragma unroll
            for (int t = 0; t < NT; t++)
#pragma unroll
                for (int s = 0; s < NS; s++)
                    acc[t] = __builtin_amdgcn_mfma_f32_16x16x32_f16(Af[s], Bf[s][t], acc[t], 0, 0, 0);
#pragma unroll
            for (int t = 0; t < NT; t++) {
                float v0 = acc[t][0], v1 = acc[t][1], v2 = acc[t][2], v3 = acc[t][3];
                if (RELU) {
                    v0 = fmaxf(v0, 0.0f); v1 = fmaxf(v1, 0.0f);
                    v2 = fmaxf(v2, 0.0f); v3 = fmaxf(v3, 0.0f);
                }
                if (STATS) {
                    ls[cb][t]  += (v0 + v1) + (v2 + v3);
                    ls2[cb][t] += (v0 * v0 + v1 * v1) + (v2 * v2 + v3 * v3);
                }
                OutT* o = Out + (size_t)(m0 + quad * 4) * FOUT + (t0 + t) * 16 + col;
                o[0]        = (OutT)v0;
                o[FOUT]     = (OutT)v1;
                o[2 * FOUT] = (OutT)v2;
                o[3 * FOUT] = (OutT)v3;
            }
        }
    }

    if (STATS) {
#pragma unroll
        for (int cb = 0; cb < NCB; cb++)
#pragma unroll
            for (int t = 0; t < NT; t++) {
                float s1 = ls[cb][t], s2 = ls2[cb][t];
                s1 += __shfl_xor(s1, 16); s1 += __shfl_xor(s1, 32);
                s2 += __shfl_xor(s2, 16); s2 += __shfl_xor(s2, 32);
                if (quad == 0) {
                    atomicAdd(&Ss[(cb * NT + t) * 16 + col], s1);
                    atomicAdd(&Ss[FOUT + (cb * NT + t) * 16 + col], s2);
                }
            }
        __syncthreads();
        float* stc = stats + (blockIdx.x & 7) * 2 * FOUT;
        for (int i = threadIdx.x; i < 2 * FOUT; i += 256) atomicAdd(&stc[i], Ss[i]);
    }
}

// ========= layer-3 BN + segmented pool (batch sorted; stats = NC copies) ======
__global__ __launch_bounds__(256) void bn_pool_kernel(const float* __restrict__ y,
        const float* __restrict__ stats, int NC, const float* __restrict__ gw,
        const float* __restrict__ bw, const int* __restrict__ batch,
        float* __restrict__ pool, int N, float invN) {
    constexpr int F = 32, CH = 64;
    int q = threadIdx.x >> 5;
    int j = threadIdx.x & 31;
    int r0 = (blockIdx.x * 8 + q) * CH;
    if (r0 >= N) return;
    int r1 = min(r0 + CH, N);
    float s1 = 0.0f, s2 = 0.0f;
    for (int c = 0; c < NC; c++) {
        s1 += stats[c * 2 * F + j];
        s2 += stats[c * 2 * F + F + j];
    }
    float mu = s1 * invN;
    float var = fmaxf(s2 * invN - mu * mu, 0.0f);
    float sc = rsqrtf(var + BN_EPS) * gw[j];
    float sh = bw[j] - mu * sc;
    int curg = batch[r0];
    float acc = 0.0f;
    for (int r = r0; r < r1; r++) {
        int g = batch[r];
        if (g != curg) {
            atomicAdd(pool + (size_t)curg * 32 + j, acc);
            acc = 0.0f;
            curg = g;
        }
        acc = fmaf(__builtin_nontemporal_load(&y[(size_t)r * 32 + j]), sc, sh + acc);
    }
    atomicAdd(pool + (size_t)curg * 32 + j, acc);
}

// ================= FC head =================
__global__ __launch_bounds__(128) void fc_kernel(const float* __restrict__ pool,
        const float* __restrict__ Wf1, const float* __restrict__ bf1,
        const float* __restrict__ Wf2, const float* __restrict__ bf2,
        const float* __restrict__ Wf3, const float* __restrict__ bf3,
        float* __restrict__ out) {
    __shared__ float zin[32];
    __shared__ float h1[128];
    __shared__ float h2[64];
    const int gidx = blockIdx.x;
    const int t = threadIdx.x;
    if (t < 32) zin[t] = pool[(size_t)gidx * 32 + t];
    __syncthreads();
    {
        float a = bf1[t];
        for (int k = 0; k < 32; k++) a = fmaf(zin[k], Wf1[k * 128 + t], a);
        h1[t] = fmaxf(a, 0.0f);
    }
    __syncthreads();
    if (t < 64) {
        float a = bf2[t];
        for (int k = 0; k < 128; k++) a = fmaf(h1[k], Wf2[k * 64 + t], a);
        h2[t] = fmaxf(a, 0.0f);
    }
    __syncthreads();
    if (t < 10) {
        float a = bf3[t];
        for (int k = 0; k < 64; k++) a = fmaf(h2[k], Wf3[k * 10 + t], a);
        out[(size_t)gidx * 10 + t] = a;
    }
}

extern "C" void kernel_launch(void* const* d_in, const int* in_sizes, int n_in,
                              void* d_out, int out_size, void* d_ws, size_t ws_size,
                              hipStream_t stream) {
    const float* x   = (const float*)d_in[0];
    const int*  ei   = (const int*)d_in[1];
    const int*  batch= (const int*)d_in[2];
    const float* W1a = (const float*)d_in[3];  const float* b1a = (const float*)d_in[4];
    const float* W1b = (const float*)d_in[5];  const float* b1b = (const float*)d_in[6];
    const float* g1  = (const float*)d_in[7];  const float* be1 = (const float*)d_in[8];
    const float* W2a = (const float*)d_in[9];  const float* b2a = (const float*)d_in[10];
    const float* W2b = (const float*)d_in[11]; const float* b2b = (const float*)d_in[12];
    const float* g2  = (const float*)d_in[13]; const float* be2 = (const float*)d_in[14];
    const float* W3a = (const float*)d_in[15]; const float* b3a = (const float*)d_in[16];
    const float* W3b = (const float*)d_in[17]; const float* b3b = (const float*)d_in[18];
    const float* g3  = (const float*)d_in[19]; const float* be3 = (const float*)d_in[20];
    const float* Wf1 = (const float*)d_in[21]; const float* bf1 = (const float*)d_in[22];
    const float* Wf2 = (const float*)d_in[23]; const float* bf2 = (const float*)d_in[24];
    const float* Wf3 = (const float*)d_in[25]; const float* bf3 = (const float*)d_in[26];

    const int N = in_sizes[2];
    const int E = in_sizes[1] / 2;
    const int G = out_size / 10;
    const int* src = ei;
    const int* dst = ei + E;

    const int NBK = (N + BMASK) >> BSHIFT;           // 391 for N=100K
    const int CHUNK = (((E + NBLK - 1) / NBLK) + 3) & ~3;  // 4-aligned

    // ---- ws layout ----
    float* B0   = (float*)d_ws;              // N*128 f32 worth (= N*256 f16)
    float* B1   = B0 + (size_t)N * 128;
    float* pool = B1 + (size_t)N * 128;      // G*32
    float* st1  = pool + (size_t)G * 32;     // 8 * 256 (8 strided copies)
    float* st2c = st1 + 2048;                // 8 * 128
    float* st3c = st2c + 1024;               // 8 * 64
    int* off    = (int*)(st3c + 512);        // N+1
    int* elist  = off + (N + 1);             // E
    float* v2   = (float*)(elist + E);       // 64
    float* v3   = v2 + 64;                   // 32
    int* btot   = (int*)(v3 + 32);           // NBK
    f16* Wh1a   = (f16*)(btot + NBK);        // 8K
    f16* Wh1b   = Wh1a + 64 * 128;           // 16K
    f16* Wh2a   = Wh1b + 128 * 128;          // 8K
    f16* Wh2b   = Wh2a + 128 * 64;           // 4K
    f16* Wh3a   = Wh2b + 64 * 64;            // 2K
    f16* Wh3b   = Wh3a + 64 * 32;            // 1K

    // ---- CSR-phase aliases in B1 (dead before B1's activation use) ----
    int* bucketed = (int*)B1;                // E ints (12.8 MB)
    int* hist     = bucketed + E;            // NBK*NBLK ints (800 KB)

    // ---- activation aliases (stream-order safe) ----
    f16* xh    = (f16*)B0;                    // N*64  [B0 slot A]
    f16* H1    = (f16*)B0 + (size_t)N * 64;   // N*128 [B0 slot B]
    f16* Y1    = (f16*)B1 + (size_t)N * 64;   // N*128 [B1 slot B] (hist dead)
    f16* Z1    = (f16*)B0;                    // N*64  [B0 slot A] (xh dead)
    f16* Y2    = (f16*)B0 + (size_t)N * 64;   // N*64  [B0 slot B] (H1 dead)
    f16* Z2    = (f16*)B0;                    // N*32  [B0 slot A] (Z1 dead)
    float* Y3  = B1 + (size_t)N * 64;         // N*32 f32 [B1 slot B] (Y1 dead)

    hipMemsetAsync(pool, 0, ((size_t)G * 32 + 2048 + 1024 + 512) * sizeof(float), stream);

    const float invN = 1.0f / (float)N;
    const int GG = 640;

    // ---- fused setup: conv + static W frags + bucket count ----
    {
        int BC = (N * 16 + 255) / 256;
        setup_count<<<BC + 116 + NBLK, 256, 0, stream>>>(
            (const float4*)x, (f16x4*)xh, N * 16,
            W1a, Wh1a, W1b, Wh1b, W2b, Wh2b, W3b, Wh3b,
            dst, hist, NBK, CHUNK, E);
    }

    // ---- CSR build ----
    bkt_bscan  <<<NBK, 512, 0, stream>>>(hist, btot);
    bkt_scatter<<<NBLK, 512, 0, stream>>>(src, dst, hist, btot, bucketed, NBK, CHUNK, E);
    bkt_csr    <<<NBK, 512, 0, stream>>>(bucketed, btot, off, elist, NBK, N, E);

    // ---- Layer 1: [gather1 + gemm1a] fused -> gemm1b(stats st1, 8 copies) ----
    gather_gemm<64, 128, false, false, f16><<<(N + 31) / 32, 256, 0, stream>>>(
        off, elist, xh, Wh1a, b1a, nullptr, nullptr, H1, nullptr, N);
    gemm_mfma<128, 128, 64, true, true, true, f16><<<GG, 256, 0, stream>>>(H1, Wh1b, b1b, Y1, st1, N);

    // ---- Layer 2 (commuted): prep -> gemm2a -> [gather2 + gemm2b(stats st2c)] ----
    layerprep_kernel<<<33, 256, 0, stream>>>(W2a, Wh2a, 128, 64, st1, 8, g1, be1, v2, invN);
    gemm_mfma<128, 64, 64, false, false, false, f16><<<GG, 256, 0, stream>>>(Y1, Wh2a, nullptr, Z1, nullptr, N);
    gather_gemm<64, 64, true, true, f16><<<(N + 31) / 32, 256, 0, stream>>>(
        off, elist, Z1, Wh2b, b2b, v2, b2a, Y2, st2c, N);

    // ---- Layer 3 (commuted): prep -> gemm3a -> [gather3 + gemm3b(stats st3c)] ----
    layerprep_kernel<<<9, 256, 0, stream>>>(W3a, Wh3a, 64, 32, st2c, 8, g2, be2, v3, invN);
    gemm_mfma<64, 32, 32, false, false, false, f16><<<GG, 256, 0, stream>>>(Y2, Wh3a, nullptr, Z2, nullptr, N);
    gather_gemm<32, 32, true, true, float><<<(N + 63) / 64, 256, 0, stream>>>(
        off, elist, Z2, Wh3b, b3b, v3, b3a, Y3, st3c, N);

    // ---- BN3 + segmented pool ----
    bn_pool_kernel<<<(N + 511) / 512, 256, 0, stream>>>(Y3, st3c, 8, g3, be3, batch, pool, N, invN);

    // ---- pooled MLP head ----
    fc_kernel<<<G, 128, 0, stream>>>(pool, Wf1, bf1, Wf2, bf2, Wf3, bf3, (float*)d_out);
}

// Round 10
// 440.403 us; speedup vs baseline: 1.4304x; 1.0795x over previous
//
#include <hip/hip_runtime.h>

#define BN_EPS 1e-5f

typedef _Float16 f16;
typedef _Float16 f16x8 __attribute__((ext_vector_type(8)));
typedef _Float16 f16x4 __attribute__((ext_vector_type(4)));
typedef float f32x4 __attribute__((ext_vector_type(4)));

#define NBLK 512      // chunks in bucket count/scatter passes
#define BSHIFT 8      // bucket = dst >> 8  (256 nodes/bucket)
#define BMASK 255

// ======= wfrag mapping: W [FIN,FOUT] f32 -> MFMA-frag-ordered f16 =============
// stats may be NC strided copies (stride 2*FIN): sum then BN-scale.
__device__ __forceinline__ void wfrag_one(const float* __restrict__ W, f16* __restrict__ out,
        int FIN, int FOUT, int f,
        const float* __restrict__ stats, int NC, const float* __restrict__ g, float invN) {
    int j = f & 7;
    int lane = (f >> 3) & 63;
    int tile = f >> 9;
    int NT = FOUT >> 4;
    int t = tile % NT, s = tile / NT;
    int k = s * 32 + (lane >> 4) * 8 + j;
    int n = t * 16 + (lane & 15);
    float w = W[(size_t)k * FOUT + n];
    if (stats) {
        float s1 = 0.0f, s2 = 0.0f;
        for (int c = 0; c < NC; c++) {
            s1 += stats[c * 2 * FIN + k];
            s2 += stats[c * 2 * FIN + FIN + k];
        }
        float mu = s1 * invN;
        float var = fmaxf(s2 * invN - mu * mu, 0.0f);
        w *= rsqrtf(var + BN_EPS) * g[k];
    }
    out[f] = (f16)w;
}

// ========== fused setup: x->f16 conv + static W frags + bucket count ==========
__global__ __launch_bounds__(256) void setup_count(const float4* __restrict__ x,
        f16x4* __restrict__ xh, int n4,
        const float* __restrict__ W1a, f16* __restrict__ Wh1a,
        const float* __restrict__ W1b, f16* __restrict__ Wh1b,
        const float* __restrict__ W2b, f16* __restrict__ Wh2b,
        const float* __restrict__ W3b, f16* __restrict__ Wh3b,
        const int* __restrict__ dst, int* __restrict__ hist,
        int NBK, int CHUNK, int E) {
    __shared__ int lh[512];
    const int BC = (n4 + 255) / 256;
    int bid = blockIdx.x;
    const int t = threadIdx.x;
    if (bid < BC) {
        int i = bid * 256 + t;
        if (i < n4) {
            float4 v = x[i];
            f16x4 o;
            o.x = (f16)v.x; o.y = (f16)v.y; o.z = (f16)v.z; o.w = (f16)v.w;
            xh[i] = o;
        }
        return;
    }
    bid -= BC;
    if (bid < 116) {
        if (bid < 32)       wfrag_one(W1a, Wh1a, 64, 128, bid * 256 + t, nullptr, 1, nullptr, 0.f);
        else if (bid < 96)  wfrag_one(W1b, Wh1b, 128, 128, (bid - 32) * 256 + t, nullptr, 1, nullptr, 0.f);
        else if (bid < 112) wfrag_one(W2b, Wh2b, 64, 64, (bid - 96) * 256 + t, nullptr, 1, nullptr, 0.f);
        else                wfrag_one(W3b, Wh3b, 32, 32, (bid - 112) * 256 + t, nullptr, 1, nullptr, 0.f);
        return;
    }
    const int blk = bid - 116;   // chunk id, one per block
    for (int r = t; r < 512; r += 256) lh[r] = 0;
    __syncthreads();
    const int e0 = blk * CHUNK, e1 = min(E, e0 + CHUNK);
    const int nq = (e1 - e0) >> 2;
    const int4* d4 = (const int4*)(dst + e0);
    for (int q = t; q < nq; q += 256) {
        int4 v = d4[q];
        atomicAdd(&lh[v.x >> BSHIFT], 1);
        atomicAdd(&lh[v.y >> BSHIFT], 1);
        atomicAdd(&lh[v.z >> BSHIFT], 1);
        atomicAdd(&lh[v.w >> BSHIFT], 1);
    }
    for (int e = e0 + (nq << 2) + t; e < e1; e += 256) atomicAdd(&lh[dst[e] >> BSHIFT], 1);
    __syncthreads();
    for (int r = t; r < NBK; r += 256) hist[r * NBLK + blk] = lh[r];
}

// per-bucket exclusive scan over chunk counts; emit bucket totals
__global__ __launch_bounds__(512) void bkt_bscan(int* __restrict__ hist,
        int* __restrict__ btot) {
    __shared__ int sh[512];
    const int b = blockIdx.x, t = threadIdx.x;
    int v = hist[b * NBLK + t];
    sh[t] = v;
    __syncthreads();
    for (int d = 1; d < 512; d <<= 1) {
        int u = (t >= d) ? sh[t - d] : 0;
        __syncthreads();
        sh[t] += u;
        __syncthreads();
    }
    hist[b * NBLK + t] = sh[t] - v;        // exclusive
    if (t == 511) btot[b] = sh[511];
}

// scatter packed (local_dst<<18 | src); computes bucket bases from btot in LDS
// NOTE: scattered stores MUST be normal stores — nt-stores on scattered 4B
// writes bypass L2 write-combining and amplify HBM writes ~16x (measured r6).
// nt-LOADS also regressed (r9): elist/dst lines are touched 4+ times within
// the unrolled loop window; evict-first policy re-fetches them from fabric.
__global__ __launch_bounds__(512) void bkt_scatter(const int* __restrict__ src,
        const int* __restrict__ dst, const int* __restrict__ hist,
        const int* __restrict__ btot, int* __restrict__ bucketed,
        int NBK, int CHUNK, int E) {
    __shared__ int sc[512];
    __shared__ int lc[512];
    const int blk = blockIdx.x, t = threadIdx.x;
    int v = (t < NBK) ? btot[t] : 0;
    sc[t] = v;
    __syncthreads();
    for (int d = 1; d < 512; d <<= 1) {
        int u = (t >= d) ? sc[t - d] : 0;
        __syncthreads();
        sc[t] += u;
        __syncthreads();
    }
    if (t < NBK) lc[t] = (sc[t] - v) + hist[t * NBLK + blk];
    __syncthreads();
    const int e0 = blk * CHUNK, e1 = min(E, e0 + CHUNK);
    const int nq = (e1 - e0) >> 2;
    const int4* d4 = (const int4*)(dst + e0);
    const int4* s4 = (const int4*)(src + e0);
    for (int q = t; q < nq; q += 512) {
        int4 d = d4[q];
        int4 s = s4[q];
        int sl;
        sl = atomicAdd(&lc[d.x >> BSHIFT], 1); bucketed[sl] = ((d.x & BMASK) << 18) | s.x;
        sl = atomicAdd(&lc[d.y >> BSHIFT], 1); bucketed[sl] = ((d.y & BMASK) << 18) | s.y;
        sl = atomicAdd(&lc[d.z >> BSHIFT], 1); bucketed[sl] = ((d.z & BMASK) << 18) | s.z;
        sl = atomicAdd(&lc[d.w >> BSHIFT], 1); bucketed[sl] = ((d.w & BMASK) << 18) | s.w;
    }
    for (int e = e0 + (nq << 2) + t; e < e1; e += 512) {
        int d = dst[e];
        int slot = atomicAdd(&lc[d >> BSHIFT], 1);
        bucketed[slot] = ((d & BMASK) << 18) | src[e];
    }
}

// per-bucket CSR finalize; computes own boff from btot in LDS
__global__ __launch_bounds__(512) void bkt_csr(const int* __restrict__ bucketed,
        const int* __restrict__ btot, int* __restrict__ off,
        int* __restrict__ elist, int NBK, int N, int E) {
    __shared__ int sc[512];
    __shared__ int lh[256];
    __shared__ int lc[256];
    __shared__ int sh[256];
    const int b = blockIdx.x, t = threadIdx.x;
    int v = (t < NBK) ? btot[t] : 0;
    sc[t] = v;
    __syncthreads();
    for (int d = 1; d < 512; d <<= 1) {
        int u = (t >= d) ? sc[t - d] : 0;
        __syncthreads();
        sc[t] += u;
        __syncthreads();
    }
    const int cnt  = btot[b];
    const int base = sc[b] - cnt;        // exclusive boff[b]
    if (b == 0 && t == 0) off[N] = E;
    const int b0 = b << BSHIFT;
    const int R = min(N - b0, 256);
    if (t < 256) lh[t] = 0;
    __syncthreads();
    for (int i = t; i < cnt; i += 512) atomicAdd(&lh[bucketed[base + i] >> 18], 1);
    __syncthreads();
    int v0 = 0;
    if (t < 256) { v0 = lh[t]; sh[t] = v0; }
    __syncthreads();
    for (int d = 1; d < 256; d <<= 1) {
        int u = 0;
        if (t < 256 && t >= d) u = sh[t - d];
        __syncthreads();
        if (t < 256) sh[t] += u;
        __syncthreads();
    }
    if (t < 256) { int ex = sh[t] - v0; lh[t] = ex; lc[t] = ex; }
    __syncthreads();
    if (t < R) off[b0 + t] = base + lh[t];
    for (int i = t; i < cnt; i += 512) {
        int p = bucketed[base + i];
        int rk = atomicAdd(&lc[p >> 18], 1);
        elist[base + rk] = p & 0x3FFFF;
    }
}

// ============ fused gather (+affine) -> LDS -> MFMA GEMM (+relu,+stats) =======
// A block gathers NPB consecutive node rows into LDS, then its 4 waves run the
// following F->FOUT GEMM on those SPB row-stripes. Stats go to 8 strided copies.
// Row-major gather: TPN lanes share one 128B row -> 8 cache lines/wave (good).
// 4-deep pipeline is the measured optimum (6-deep cost occupancy and regressed;
// nt hints on elist/outputs regressed — default cache policy wins, r6/r9).
template<int F, int FOUT, bool STATS, bool AFFINE, typename OutT>
__global__ __launch_bounds__(256) void gather_gemm(const int* __restrict__ off,
        const int* __restrict__ elist, const f16* __restrict__ in,
        const f16* __restrict__ Wf, const float* __restrict__ bias,
        const float* __restrict__ av, const float* __restrict__ ab,
        OutT* __restrict__ Out, float* __restrict__ stats, int N) {
    constexpr int TPN = F / 8;         // lanes per node in gather
    constexpr int NPB = 256 / TPN;     // nodes per block
    constexpr int SPB = NPB / 16;      // 16-row stripes per block
    constexpr int WPS = 4 / SPB;       // waves per stripe
    constexpr int NTF = FOUT / 16;     // total n-tiles
    constexpr int NTW = NTF / WPS;     // n-tiles per wave
    constexpr int NS = F / 32;         // k-steps
    constexpr int LDW = F + 8;         // LDS row stride (f16), +16B pad
    __shared__ f16 Hl[NPB * LDW];
    __shared__ float Ss[STATS ? 2 * FOUT : 1];
    if (STATS) for (int z = threadIdx.x; z < 2 * FOUT; z += 256) Ss[z] = 0.0f;

    const int base = blockIdx.x * NPB;
    const int rl = threadIdx.x / TPN;
    const int i = base + rl;
    const int l = threadIdx.x & (TPN - 1);
    if (i < N) {
        const int j0 = l * 8;
        const f16x8* __restrict__ inv = (const f16x8*)in;
        f16x8 s = inv[(size_t)i * TPN + l];
        float a[8];
#pragma unroll
        for (int u = 0; u < 8; u++) a[u] = (float)s[u];
        int k = off[i], e = off[i + 1];
        const float cnt = (float)(e - k + 1);
        f16x8 c0, c1, c2, c3;
        if (k + 4 <= e) {
            c0 = inv[(size_t)elist[k + 0] * TPN + l];
            c1 = inv[(size_t)elist[k + 1] * TPN + l];
            c2 = inv[(size_t)elist[k + 2] * TPN + l];
            c3 = inv[(size_t)elist[k + 3] * TPN + l];
            k += 4;
            for (; k + 4 <= e; k += 4) {
                f16x8 d0 = inv[(size_t)elist[k + 0] * TPN + l];
                f16x8 d1 = inv[(size_t)elist[k + 1] * TPN + l];
                f16x8 d2 = inv[(size_t)elist[k + 2] * TPN + l];
                f16x8 d3 = inv[(size_t)elist[k + 3] * TPN + l];
#pragma unroll
                for (int u = 0; u < 8; u++)
                    a[u] += ((float)c0[u] + (float)c1[u]) + ((float)c2[u] + (float)c3[u]);
                c0 = d0; c1 = d1; c2 = d2; c3 = d3;
            }
#pragma unroll
            for (int u = 0; u < 8; u++)
                a[u] += ((float)c0[u] + (float)c1[u]) + ((float)c2[u] + (float)c3[u]);
        }
        for (; k < e; k++) {
            f16x8 p = inv[(size_t)elist[k] * TPN + l];
#pragma unroll
            for (int u = 0; u < 8; u++) a[u] += (float)p[u];
        }
        if (AFFINE) {
            float4 vv0 = *(const float4*)(av + j0);
            float4 vv1 = *(const float4*)(av + j0 + 4);
            float4 bb0 = *(const float4*)(ab + j0);
            float4 bb1 = *(const float4*)(ab + j0 + 4);
            a[0] = fmaxf(fmaf(cnt, vv0.x, a[0] + bb0.x), 0.0f);
            a[1] = fmaxf(fmaf(cnt, vv0.y, a[1] + bb0.y), 0.0f);
            a[2] = fmaxf(fmaf(cnt, vv0.z, a[2] + bb0.z), 0.0f);
            a[3] = fmaxf(fmaf(cnt, vv0.w, a[3] + bb0.w), 0.0f);
            a[4] = fmaxf(fmaf(cnt, vv1.x, a[4] + bb1.x), 0.0f);
            a[5] = fmaxf(fmaf(cnt, vv1.y, a[5] + bb1.y), 0.0f);
            a[6] = fmaxf(fmaf(cnt, vv1.z, a[6] + bb1.z), 0.0f);
            a[7] = fmaxf(fmaf(cnt, vv1.w, a[7] + bb1.w), 0.0f);
        }
        f16x8 o;
#pragma unroll
        for (int u = 0; u < 8; u++) o[u] = (f16)a[u];
        *(f16x8*)&Hl[rl * LDW + j0] = o;
    }
    __syncthreads();

    const int wid = threadIdx.x >> 6;
    const int lane = threadIdx.x & 63;
    const int col = lane & 15;
    const int quad = lane >> 4;
    const int sid = wid / WPS;
    const int cg = wid % WPS;
    const int m0 = base + sid * 16;
    if (m0 < N) {
        f16x8 Bf[NS][NTW];
#pragma unroll
        for (int s = 0; s < NS; s++)
#pragma unroll
            for (int t = 0; t < NTW; t++)
                Bf[s][t] = *(const f16x8*)&Wf[((s * NTF + cg * NTW + t) << 9) + (lane << 3)];
        f32x4 acc[NTW];
#pragma unroll
        for (int t = 0; t < NTW; t++) {
            float b = bias[(cg * NTW + t) * 16 + col];
            acc[t] = (f32x4){b, b, b, b};
        }
        f16x8 Af[NS];
        const int rbase = (sid * 16 + col) * LDW + quad * 8;
#pragma unroll
        for (int s = 0; s < NS; s++) Af[s] = *(const f16x8*)&Hl[rbase + s * 32];
#pragma unroll
        for (int t = 0; t < NTW; t++)
#pragma unroll
            for (int s = 0; s < NS; s++)
                acc[t] = __builtin_amdgcn_mfma_f32_16x16x32_f16(Af[s], Bf[s][t], acc[t], 0, 0, 0);
#pragma unroll
        for (int t = 0; t < NTW; t++) {
            float v0 = fmaxf(acc[t][0], 0.0f);
            float v1 = fmaxf(acc[t][1], 0.0f);
            float v2 = fmaxf(acc[t][2], 0.0f);
            float v3 = fmaxf(acc[t][3], 0.0f);
            OutT* o = Out + (size_t)(m0 + quad * 4) * FOUT + (cg * NTW + t) * 16 + col;
            o[0]        = (OutT)v0;
            o[FOUT]     = (OutT)v1;
            o[2 * FOUT] = (OutT)v2;
            o[3 * FOUT] = (OutT)v3;
            if (STATS) {
                float s1 = (v0 + v1) + (v2 + v3);
                float s2 = (v0 * v0 + v1 * v1) + (v2 * v2 + v3 * v3);
                s1 += __shfl_xor(s1, 16); s1 += __shfl_xor(s1, 32);
                s2 += __shfl_xor(s2, 16); s2 += __shfl_xor(s2, 32);
                if (quad == 0) {
                    atomicAdd(&Ss[(cg * NTW + t) * 16 + col], s1);
                    atomicAdd(&Ss[FOUT + (cg * NTW + t) * 16 + col], s2);
                }
            }
        }
    }
    if (STATS) {
        __syncthreads();
        float* stc = stats + (blockIdx.x & 7) * 2 * FOUT;
        for (int z = threadIdx.x; z < 2 * FOUT; z += 256) atomicAdd(&stc[z], Ss[z]);
    }
}

// ===== fused layer prep: block 0 computes v[]; blocks 1.. do scaled wfrag =====
// Block 0 parallelizes the stats reduction across k (one thread per k-channel,
// sc/sh stashed in LDS): the serial FIN x NC form was a 76us straggler.
__global__ __launch_bounds__(256) void layerprep_kernel(const float* __restrict__ W,
        f16* __restrict__ Wh, int FIN, int FOUT,
        const float* __restrict__ stats, int NC, const float* __restrict__ g,
        const float* __restrict__ be, float* __restrict__ v, float invN) {
    if (blockIdx.x == 0) {
        __shared__ float sh_s[128];
        const int t = threadIdx.x;
        if (t < FIN) {
            float s1 = 0.0f, s2 = 0.0f;
            for (int c = 0; c < NC; c++) {
                s1 += stats[c * 2 * FIN + t];
                s2 += stats[c * 2 * FIN + FIN + t];
            }
            float mu = s1 * invN;
            float var = fmaxf(s2 * invN - mu * mu, 0.0f);
            float sc = rsqrtf(var + BN_EPS) * g[t];
            sh_s[t] = be[t] - mu * sc;
        }
        __syncthreads();
        for (int j = t; j < FOUT; j += 256) {
            float acc = 0.0f;
            for (int k = 0; k < FIN; k++)
                acc = fmaf(sh_s[k], W[(size_t)k * FOUT + j], acc);
            v[j] = acc;
        }
        return;
    }
    int f = (blockIdx.x - 1) * 256 + threadIdx.x;
    if (f < FIN * FOUT) wfrag_one(W, Wh, FIN, FOUT, f, stats, NC, g, invN);
}

// ======= standalone MFMA GEMM (pre-fragged W, column-block loop INSIDE) =======
// Column blocks iterate inside the stripe loop so A streams exactly once from
// HBM; Bf reloads per cb come from the L2-hot 32KB weight array. Stats go to
// 8 strided copies to avoid single-line atomic contention.
template<int FIN, int FOUT, int CT, bool STATS, bool RELU, bool BIAS, typename OutT>
__global__ __launch_bounds__(256) void gemm_mfma(const f16* __restrict__ A,
        const f16* __restrict__ Wf, const float* __restrict__ bias,
        OutT* __restrict__ Out, float* __restrict__ stats, int N) {
    constexpr int NS = FIN / 32;
    constexpr int NTF = FOUT / 16;
    constexpr int NT = CT / 16;
    constexpr int NCB = FOUT / CT;
    __shared__ float Ss[STATS ? 2 * FOUT : 1];
    if (STATS) {
        for (int i = threadIdx.x; i < 2 * FOUT; i += 256) Ss[i] = 0.0f;
        __syncthreads();
    }
    const int rb = blockIdx.x;
    const int RB = gridDim.x;
    const int wid = threadIdx.x >> 6;
    const int lane = threadIdx.x & 63;
    const int col = lane & 15;
    const int quad = lane >> 4;

    float bj[NCB][NT];
#pragma unroll
    for (int cb = 0; cb < NCB; cb++)
#pragma unroll
        for (int t = 0; t < NT; t++)
            bj[cb][t] = BIAS ? bias[(cb * NT + t) * 16 + col] : 0.0f;

    float ls[NCB][NT], ls2[NCB][NT];
#pragma unroll
    for (int cb = 0; cb < NCB; cb++)
#pragma unroll
        for (int t = 0; t < NT; t++) { ls[cb][t] = 0.0f; ls2[cb][t] = 0.0f; }

    const int S = N >> 4;
    for (int sidx = rb * 4 + wid; sidx < S; sidx += RB * 4) {
        const int m0 = sidx << 4;
        const f16* a0 = A + (size_t)(m0 + col) * FIN + (quad << 3);
        f16x8 Af[NS];
#pragma unroll
        for (int s = 0; s < NS; s++) Af[s] = *(const f16x8*)(a0 + s * 32);
#pragma unroll
        for (int cb = 0; cb < NCB; cb++) {
            const int t0 = cb * NT;
            f16x8 Bf[NS][NT];
#pragma unroll
            for (int s = 0; s < NS; s++)
#pragma unroll
                for (int t = 0; t < NT; t++)
                    Bf[s][t] = *(const f16x8*)&Wf[((s * NTF + t0 + t) << 9) + (lane << 3)];
            f32x4 acc[NT];
#pragma unroll
            for (int t = 0; t < NT; t++) acc[t] = (f32x4){bj[cb][t], bj[cb][t], bj[cb][t], bj[cb][t]};
#pragma unroll
            for (int t = 0; t < NT; t++)
#pragma unroll
                for (int s = 0; s < NS; s++)
                    acc[t] = __builtin_amdgcn_mfma_f32_16x16x32_f16(Af[s], Bf[s][t], acc[t], 0, 0, 0);
#pragma unroll
            for (int t = 0; t < NT; t++) {
                float v0 = acc[t][0], v1 = acc[t][1], v2 = acc[t][2], v3 = acc[t][3];
                if (RELU) {
                    v0 = fmaxf(v0, 0.0f); v1 = fmaxf(v1, 0.0f);
                    v2 = fmaxf(v2, 0.0f); v3 = fmaxf(v3, 0.0f);
                }
                if (STATS) {
                    ls[cb][t]  += (v0 + v1) + (v2 + v3);
                    ls2[cb][t] += (v0 * v0 + v1 * v1) + (v2 * v2 + v3 * v3);
                }
                OutT* o = Out + (size_t)(m0 + quad * 4) * FOUT + (t0 + t) * 16 + col;
                o[0]        = (OutT)v0;
                o[FOUT]     = (OutT)v1;
                o[2 * FOUT] = (OutT)v2;
                o[3 * FOUT] = (OutT)v3;
            }
        }
    }

    if (STATS) {
#pragma unroll
        for (int cb = 0; cb < NCB; cb++)
#pragma unroll
            for (int t = 0; t < NT; t++) {
                float s1 = ls[cb][t], s2 = ls2[cb][t];
                s1 += __shfl_xor(s1, 16); s1 += __shfl_xor(s1, 32);
                s2 += __shfl_xor(s2, 16); s2 += __shfl_xor(s2, 32);
                if (quad == 0) {
                    atomicAdd(&Ss[(cb * NT + t) * 16 + col], s1);
                    atomicAdd(&Ss[FOUT + (cb * NT + t) * 16 + col], s2);
                }
            }
        __syncthreads();
        float* stc = stats + (blockIdx.x & 7) * 2 * FOUT;
        for (int i = threadIdx.x; i < 2 * FOUT; i += 256) atomicAdd(&stc[i], Ss[i]);
    }
}

// ========= layer-3 BN + segmented pool (batch sorted; stats = NC copies) ======
__global__ __launch_bounds__(256) void bn_pool_kernel(const float* __restrict__ y,
        const float* __restrict__ stats, int NC, const float* __restrict__ gw,
        const float* __restrict__ bw, const int* __restrict__ batch,
        float* __restrict__ pool, int N, float invN) {
    constexpr int F = 32, CH = 64;
    int q = threadIdx.x >> 5;
    int j = threadIdx.x & 31;
    int r0 = (blockIdx.x * 8 + q) * CH;
    if (r0 >= N) return;
    int r1 = min(r0 + CH, N);
    float s1 = 0.0f, s2 = 0.0f;
    for (int c = 0; c < NC; c++) {
        s1 += stats[c * 2 * F + j];
        s2 += stats[c * 2 * F + F + j];
    }
    float mu = s1 * invN;
    float var = fmaxf(s2 * invN - mu * mu, 0.0f);
    float sc = rsqrtf(var + BN_EPS) * gw[j];
    float sh = bw[j] - mu * sc;
    int curg = batch[r0];
    float acc = 0.0f;
    for (int r = r0; r < r1; r++) {
        int g = batch[r];
        if (g != curg) {
            atomicAdd(pool + (size_t)curg * 32 + j, acc);
            acc = 0.0f;
            curg = g;
        }
        acc = fmaf(y[(size_t)r * 32 + j], sc, sh + acc);
    }
    atomicAdd(pool + (size_t)curg * 32 + j, acc);
}

// ================= FC head =================
__global__ __launch_bounds__(128) void fc_kernel(const float* __restrict__ pool,
        const float* __restrict__ Wf1, const float* __restrict__ bf1,
        const float* __restrict__ Wf2, const float* __restrict__ bf2,
        const float* __restrict__ Wf3, const float* __restrict__ bf3,
        float* __restrict__ out) {
    __shared__ float zin[32];
    __shared__ float h1[128];
    __shared__ float h2[64];
    const int gidx = blockIdx.x;
    const int t = threadIdx.x;
    if (t < 32) zin[t] = pool[(size_t)gidx * 32 + t];
    __syncthreads();
    {
        float a = bf1[t];
        for (int k = 0; k < 32; k++) a = fmaf(zin[k], Wf1[k * 128 + t], a);
        h1[t] = fmaxf(a, 0.0f);
    }
    __syncthreads();
    if (t < 64) {
        float a = bf2[t];
        for (int k = 0; k < 128; k++) a = fmaf(h1[k], Wf2[k * 64 + t], a);
        h2[t] = fmaxf(a, 0.0f);
    }
    __syncthreads();
    if (t < 10) {
        float a = bf3[t];
        for (int k = 0; k < 64; k++) a = fmaf(h2[k], Wf3[k * 10 + t], a);
        out[(size_t)gidx * 10 + t] = a;
    }
}

extern "C" void kernel_launch(void* const* d_in, const int* in_sizes, int n_in,
                              void* d_out, int out_size, void* d_ws, size_t ws_size,
                              hipStream_t stream) {
    const float* x   = (const float*)d_in[0];
    const int*  ei   = (const int*)d_in[1];
    const int*  batch= (const int*)d_in[2];
    const float* W1a = (const float*)d_in[3];  const float* b1a = (const float*)d_in[4];
    const float* W1b = (const float*)d_in[5];  const float* b1b = (const float*)d_in[6];
    const float* g1  = (const float*)d_in[7];  const float* be1 = (const float*)d_in[8];
    const float* W2a = (const float*)d_in[9];  const float* b2a = (const float*)d_in[10];
    const float* W2b = (const float*)d_in[11]; const float* b2b = (const float*)d_in[12];
    const float* g2  = (const float*)d_in[13]; const float* be2 = (const float*)d_in[14];
    const float* W3a = (const float*)d_in[15]; const float* b3a = (const float*)d_in[16];
    const float* W3b = (const float*)d_in[17]; const float* b3b = (const float*)d_in[18];
    const float* g3  = (const float*)d_in[19]; const float* be3 = (const float*)d_in[20];
    const float* Wf1 = (const float*)d_in[21]; const float* bf1 = (const float*)d_in[22];
    const float* Wf2 = (const float*)d_in[23]; const float* bf2 = (const float*)d_in[24];
    const float* Wf3 = (const float*)d_in[25]; const float* bf3 = (const float*)d_in[26];

    const int N = in_sizes[2];
    const int E = in_sizes[1] / 2;
    const int G = out_size / 10;
    const int* src = ei;
    const int* dst = ei + E;

    const int NBK = (N + BMASK) >> BSHIFT;           // 391 for N=100K
    const int CHUNK = (((E + NBLK - 1) / NBLK) + 3) & ~3;  // 4-aligned

    // ---- ws layout ----
    float* B0   = (float*)d_ws;              // N*128 f32 worth (= N*256 f16)
    float* B1   = B0 + (size_t)N * 128;
    float* pool = B1 + (size_t)N * 128;      // G*32
    float* st1  = pool + (size_t)G * 32;     // 8 * 256 (8 strided copies)
    float* st2c = st1 + 2048;                // 8 * 128
    float* st3c = st2c + 1024;               // 8 * 64
    int* off    = (int*)(st3c + 512);        // N+1
    int* elist  = off + (N + 1);             // E
    float* v2   = (float*)(elist + E);       // 64
    float* v3   = v2 + 64;                   // 32
    int* btot   = (int*)(v3 + 32);           // NBK
    f16* Wh1a   = (f16*)(btot + NBK);        // 8K
    f16* Wh1b   = Wh1a + 64 * 128;           // 16K
    f16* Wh2a   = Wh1b + 128 * 128;          // 8K
    f16* Wh2b   = Wh2a + 128 * 64;           // 4K
    f16* Wh3a   = Wh2b + 64 * 64;            // 2K
    f16* Wh3b   = Wh3a + 64 * 32;            // 1K

    // ---- CSR-phase aliases in B1 (dead before B1's activation use) ----
    int* bucketed = (int*)B1;                // E ints (12.8 MB)
    int* hist     = bucketed + E;            // NBK*NBLK ints (800 KB)

    // ---- activation aliases (stream-order safe) ----
    f16* xh    = (f16*)B0;                    // N*64  [B0 slot A]
    f16* H1    = (f16*)B0 + (size_t)N * 64;   // N*128 [B0 slot B]
    f16* Y1    = (f16*)B1 + (size_t)N * 64;   // N*128 [B1 slot B] (hist dead)
    f16* Z1    = (f16*)B0;                    // N*64  [B0 slot A] (xh dead)
    f16* Y2    = (f16*)B0 + (size_t)N * 64;   // N*64  [B0 slot B] (H1 dead)
    f16* Z2    = (f16*)B0;                    // N*32  [B0 slot A] (Z1 dead)
    float* Y3  = B1 + (size_t)N * 64;         // N*32 f32 [B1 slot B] (Y1 dead)

    hipMemsetAsync(pool, 0, ((size_t)G * 32 + 2048 + 1024 + 512) * sizeof(float), stream);

    const float invN = 1.0f / (float)N;
    const int GG = 640;

    // ---- fused setup: conv + static W frags + bucket count ----
    {
        int BC = (N * 16 + 255) / 256;
        setup_count<<<BC + 116 + NBLK, 256, 0, stream>>>(
            (const float4*)x, (f16x4*)xh, N * 16,
            W1a, Wh1a, W1b, Wh1b, W2b, Wh2b, W3b, Wh3b,
            dst, hist, NBK, CHUNK, E);
    }

    // ---- CSR build ----
    bkt_bscan  <<<NBK, 512, 0, stream>>>(hist, btot);
    bkt_scatter<<<NBLK, 512, 0, stream>>>(src, dst, hist, btot, bucketed, NBK, CHUNK, E);
    bkt_csr    <<<NBK, 512, 0, stream>>>(bucketed, btot, off, elist, NBK, N, E);

    // ---- Layer 1: [gather1 + gemm1a] fused -> gemm1b(stats st1, 8 copies) ----
    gather_gemm<64, 128, false, false, f16><<<(N + 31) / 32, 256, 0, stream>>>(
        off, elist, xh, Wh1a, b1a, nullptr, nullptr, H1, nullptr, N);
    gemm_mfma<128, 128, 64, true, true, true, f16><<<GG, 256, 0, stream>>>(H1, Wh1b, b1b, Y1, st1, N);

    // ---- Layer 2 (commuted): prep -> gemm2a -> [gather2 + gemm2b(stats st2c)] ----
    layerprep_kernel<<<33, 256, 0, stream>>>(W2a, Wh2a, 128, 64, st1, 8, g1, be1, v2, invN);
    gemm_mfma<128, 64, 64, false, false, false, f16><<<GG, 256, 0, stream>>>(Y1, Wh2a, nullptr, Z1, nullptr, N);
    gather_gemm<64, 64, true, true, f16><<<(N + 31) / 32, 256, 0, stream>>>(
        off, elist, Z1, Wh2b, b2b, v2, b2a, Y2, st2c, N);

    // ---- Layer 3 (commuted): prep -> gemm3a -> [gather3 + gemm3b(stats st3c)] ----
    layerprep_kernel<<<9, 256, 0, stream>>>(W3a, Wh3a, 64, 32, st2c, 8, g2, be2, v3, invN);
    gemm_mfma<64, 32, 32, false, false, false, f16><<<GG, 256, 0, stream>>>(Y2, Wh3a, nullptr, Z2, nullptr, N);
    gather_gemm<32, 32, true, true, float><<<(N + 63) / 64, 256, 0, stream>>>(
        off, elist, Z2, Wh3b, b3b, v3, b3a, Y3, st3c, N);

    // ---- BN3 + segmented pool ----
    bn_pool_kernel<<<(N + 511) / 512, 256, 0, stream>>>(Y3, st3c, 8, g3, be3, batch, pool, N, invN);

    // ---- pooled MLP head ----
    fc_kernel<<<G, 128, 0, stream>>>(pool, Wf1, bf1, Wf2, bf2, Wf3, bf3, (float*)d_out);
}